// Round 11
// baseline (1464.804 us; speedup 1.0000x reference)
//
#include <hip/hip_runtime.h>

#define DIVUP(a,b) (((a)+(b)-1)/(b))

// ---------------------------------------------------------------------------
__global__ void bcast_anchor_kernel(const float* __restrict__ a, float* __restrict__ out) {
    int i = blockIdx.x * 256 + threadIdx.x;   // over 3*127*127 = 48387
    int b = blockIdx.y;
    if (i < 48387) out[b * 48387 + i] = a[i];
}

// ---------------------------------------------------------------------------
// conv K=4 s=2 VALID + ReLU: OCT ocs x 4 x-pixels per thread (direct form).
// OSTR = output row stride (== Wout normally; 128 for the padded F1 layout).
// grid: (DIVUP(Hout*ceil(Wout/4),256), Cout/OCT, B). Tail x-tiles shift left.
// R6 lesson: OCT=4 where OCT=8 would collapse the grid below ~1024 blocks.
// R9: OCT=8 pays for Cin=3 L1 convs (6.4 -> 12.8 FMA/load, grid stays big).
template<int OCT, bool VEC>
__global__ void conv4s2_relu_k(const float* __restrict__ in, const float* __restrict__ w,
                               const float* __restrict__ bias, float* __restrict__ out,
                               int Cin, int Hin, int Win, int Hout, int Wout, int OSTR)
{
    const int ocg = blockIdx.y, b = blockIdx.z, Cout = gridDim.y * OCT;
    const int TX = (Wout + 3) >> 2;
    const int t  = blockIdx.x * 256 + threadIdx.x;
    if (t >= Hout * TX) return;
    const int oy = t / TX, tx = t - oy * TX;
    int ox0 = tx * 4; if (ox0 > Wout - 4) ox0 = Wout - 4;

    const float* ip = in + ((size_t)(b * Cin) * Hin + 2 * oy) * Win + 2 * ox0;
    const float* wb = w + (size_t)ocg * OCT * Cin * 16;
    float acc[OCT][4];
    #pragma unroll
    for (int o = 0; o < OCT; ++o) {
        float z = bias[ocg * OCT + o];
        acc[o][0] = z; acc[o][1] = z; acc[o][2] = z; acc[o][3] = z;
    }
    for (int ic = 0; ic < Cin; ++ic) {
        const float* r = ip + (size_t)ic * Hin * Win;
        #pragma unroll
        for (int ky = 0; ky < 4; ++ky) {
            const float* rr = r + ky * Win;
            float x0,x1,x2,x3,x4,x5,x6,x7,x8,x9;
            if (VEC) {
                const float2* rv = (const float2*)rr;
                float2 p0=rv[0], p1=rv[1], p2=rv[2], p3=rv[3], p4=rv[4];
                x0=p0.x; x1=p0.y; x2=p1.x; x3=p1.y; x4=p2.x;
                x5=p2.y; x6=p3.x; x7=p3.y; x8=p4.x; x9=p4.y;
            } else {
                x0=rr[0]; x1=rr[1]; x2=rr[2]; x3=rr[3]; x4=rr[4];
                x5=rr[5]; x6=rr[6]; x7=rr[7]; x8=rr[8]; x9=rr[9];
            }
            #pragma unroll
            for (int o = 0; o < OCT; ++o) {
                const float* wk = wb + ((o * Cin + ic) * 4 + ky) * 4;  // uniform -> s_load
                float w0 = wk[0], w1 = wk[1], w2 = wk[2], w3 = wk[3];
                acc[o][0] = fmaf(x0, w0, fmaf(x1, w1, fmaf(x2, w2, fmaf(x3, w3, acc[o][0]))));
                acc[o][1] = fmaf(x2, w0, fmaf(x3, w1, fmaf(x4, w2, fmaf(x5, w3, acc[o][1]))));
                acc[o][2] = fmaf(x4, w0, fmaf(x5, w1, fmaf(x6, w2, fmaf(x7, w3, acc[o][2]))));
                acc[o][3] = fmaf(x6, w0, fmaf(x7, w1, fmaf(x8, w2, fmaf(x9, w3, acc[o][3]))));
            }
        }
    }
    float* op = out + (((size_t)b * Cout + ocg * OCT) * Hout + oy) * OSTR + ox0;
    #pragma unroll
    for (int o = 0; o < OCT; ++o) {
        float* q = op + (size_t)o * Hout * OSTR;
        q[0] = fmaxf(acc[o][0], 0.0f); q[1] = fmaxf(acc[o][1], 0.0f);
        q[2] = fmaxf(acc[o][2], 0.0f); q[3] = fmaxf(acc[o][3], 0.0f);
    }
}

// ---------------------------------------------------------------------------
// pair form for sia-L2, padded (row stride 128) F1 layout, SW-PIPELINED with
// __launch_bounds__(256, 1).
// R8 failed because the default allocator targets 8 waves/SIMD (64-VGPR cap)
// and SPILLED the ping-pong buffers (WRITE_SIZE 700 MB, 311 us).  The bounds
// declaration lifts the cap to 256 VGPR: ~170 VGPR fits, waves/SIMD 4 -> 3
// (small TLP loss) in exchange for ILP that hides the ~300-cy per-ic load
// stall (the source of the 70% VALUBusy duty cycle: 1024 FMA-cy / 1324).
// Success signature: VGPR_Count 150-220, WRITE_SIZE ~31 MB, dur < 110 us.
// Spill signature (falsifier): WRITE_SIZE >> 100 MB -> revert to R10 config.
// FMA order per output element unchanged (ic asc, rr6 asc) -> bit-identical.
// grid: (2, 16, B) x 256 thr (496/512 active).
__global__ void __launch_bounds__(256, 1)
conv4s2_pair4_k(const float* __restrict__ in, const float* __restrict__ w,
                const float* __restrict__ bias, float* __restrict__ out,
                int Cin, int Hin, int Hout, int Wout)
{
    const int ocg = blockIdx.y, b = blockIdx.z, Cout = gridDim.y * 4;
    const int TX = (Wout + 3) >> 2;
    const int H2 = Hout >> 1;
    const int t  = blockIdx.x * 256 + threadIdx.x;
    if (t >= H2 * TX) return;
    const int oyp = t / TX, tx = t - oyp * TX;
    int ox0 = tx * 4; if (ox0 > Wout - 4) ox0 = Wout - 4;   // Wout even -> ox0 even
    const int oy0 = 2 * oyp;

    const float* ip = in + ((size_t)(b * Cin) * Hin + 2 * oy0) * 128 + 2 * ox0;
    const float* wb = w + (size_t)ocg * 4 * Cin * 16;
    float acc[4][2][4];                       // [oc][row][px]
    #pragma unroll
    for (int o = 0; o < 4; ++o) {
        float z = bias[ocg * 4 + o];
        #pragma unroll
        for (int p = 0; p < 2; ++p) {
            acc[o][p][0] = z; acc[o][p][1] = z; acc[o][p][2] = z; acc[o][p][3] = z;
        }
    }

    float4 raA[6], rbA[6]; float2 rcA[6];     // ping buffer
    float4 raB[6], rbB[6]; float2 rcB[6];     // pong buffer

#define PAIR4_LOAD(RA, RB, RC, IC) { \
        const float* r_ = ip + (size_t)(IC) * Hin * 128; \
        _Pragma("unroll") \
        for (int q_ = 0; q_ < 6; ++q_) { \
            const float* row_ = r_ + q_ * 128; \
            RA[q_] = *(const float4*)row_; \
            RB[q_] = *(const float4*)(row_ + 4); \
            RC[q_] = *(const float2*)(row_ + 8); \
        } }

#define PAIR4_COMP(RA, RB, RC, IC) { \
        _Pragma("unroll") \
        for (int rr6_ = 0; rr6_ < 6; ++rr6_) { \
            float x0=RA[rr6_].x, x1=RA[rr6_].y, x2=RA[rr6_].z, x3=RA[rr6_].w; \
            float x4=RB[rr6_].x, x5=RB[rr6_].y, x6=RB[rr6_].z, x7=RB[rr6_].w; \
            float x8=RC[rr6_].x, x9=RC[rr6_].y; \
            _Pragma("unroll") \
            for (int o_ = 0; o_ < 4; ++o_) { \
                if (rr6_ < 4) {               /* top row: ky = rr6 */ \
                    const float* wk = wb + ((o_ * Cin + (IC)) * 4 + rr6_) * 4;   /* s_load */ \
                    float w0=wk[0], w1=wk[1], w2=wk[2], w3=wk[3]; \
                    acc[o_][0][0] = fmaf(x0,w0, fmaf(x1,w1, fmaf(x2,w2, fmaf(x3,w3, acc[o_][0][0])))); \
                    acc[o_][0][1] = fmaf(x2,w0, fmaf(x3,w1, fmaf(x4,w2, fmaf(x5,w3, acc[o_][0][1])))); \
                    acc[o_][0][2] = fmaf(x4,w0, fmaf(x5,w1, fmaf(x6,w2, fmaf(x7,w3, acc[o_][0][2])))); \
                    acc[o_][0][3] = fmaf(x6,w0, fmaf(x7,w1, fmaf(x8,w2, fmaf(x9,w3, acc[o_][0][3])))); \
                } \
                if (rr6_ >= 2) {              /* bottom row: ky = rr6-2 */ \
                    const float* wk = wb + ((o_ * Cin + (IC)) * 4 + (rr6_ - 2)) * 4; \
                    float w0=wk[0], w1=wk[1], w2=wk[2], w3=wk[3]; \
                    acc[o_][1][0] = fmaf(x0,w0, fmaf(x1,w1, fmaf(x2,w2, fmaf(x3,w3, acc[o_][1][0])))); \
                    acc[o_][1][1] = fmaf(x2,w0, fmaf(x3,w1, fmaf(x4,w2, fmaf(x5,w3, acc[o_][1][1])))); \
                    acc[o_][1][2] = fmaf(x4,w0, fmaf(x5,w1, fmaf(x6,w2, fmaf(x7,w3, acc[o_][1][2])))); \
                    acc[o_][1][3] = fmaf(x6,w0, fmaf(x7,w1, fmaf(x8,w2, fmaf(x9,w3, acc[o_][1][3])))); \
                } \
            } \
        } }

    // prologue - steady state (2 ic per iter) - epilogue; ic order preserved
    PAIR4_LOAD(raA, rbA, rcA, 0);
    #pragma unroll 1
    for (int ic = 0; ic <= Cin - 4; ic += 2) {
        PAIR4_LOAD(raB, rbB, rcB, ic + 1);
        PAIR4_COMP(raA, rbA, rcA, ic);
        PAIR4_LOAD(raA, rbA, rcA, ic + 2);
        PAIR4_COMP(raB, rbB, rcB, ic + 1);
    }
    PAIR4_LOAD(raB, rbB, rcB, Cin - 1);
    PAIR4_COMP(raA, rbA, rcA, Cin - 2);
    PAIR4_COMP(raB, rbB, rcB, Cin - 1);
#undef PAIR4_LOAD
#undef PAIR4_COMP

    float* op = out + (((size_t)b * Cout + ocg * 4) * Hout + oy0) * Wout + ox0;
    #pragma unroll
    for (int o = 0; o < 4; ++o) {
        float* q = op + (size_t)o * Hout * Wout;
        q[0]        = fmaxf(acc[o][0][0], 0.0f); q[1]        = fmaxf(acc[o][0][1], 0.0f);
        q[2]        = fmaxf(acc[o][0][2], 0.0f); q[3]        = fmaxf(acc[o][0][3], 0.0f);
        q[Wout]     = fmaxf(acc[o][1][0], 0.0f); q[Wout + 1] = fmaxf(acc[o][1][1], 0.0f);
        q[Wout + 2] = fmaxf(acc[o][1][2], 0.0f); q[Wout + 3] = fmaxf(acc[o][1][3], 0.0f);
    }
}

// ---------------------------------------------------------------------------
// fused VAE head
__global__ void vae_head_kernel(const float* __restrict__ h, const float* __restrict__ mw,
                                const float* __restrict__ mb, const float* __restrict__ lw,
                                const float* __restrict__ lb, const float* __restrict__ eps,
                                float* __restrict__ mu_out, float* __restrict__ lv_out,
                                float* __restrict__ z_out)
{
    const int idx = blockIdx.x * 256 + threadIdx.x;   // over 64*32*196
    if (idx >= 64 * 32 * 196) return;
    const int p  = idx % 196;
    const int oc = (idx / 196) % 32;
    const int b  = idx / (196 * 32);
    const float* hb = h + (b * 64) * 196 + p;
    float am = mb[oc], al = lb[oc];
    for (int ic = 0; ic < 64; ++ic) {
        float hv = hb[ic * 196];
        am = fmaf(hv, mw[oc * 64 + ic], am);
        al = fmaf(hv, lw[oc * 64 + ic], al);
    }
    mu_out[idx] = am;
    lv_out[idx] = al;
    z_out[idx]  = fmaf(eps[idx], expf(0.5f * al), am);
}

// ---------------------------------------------------------------------------
__global__ void conv1x1_relu_kernel(const float* __restrict__ in, const float* __restrict__ w,
                                    const float* __restrict__ bias, float* __restrict__ out,
                                    int Cin, int Cout, int HW, int total)
{
    const int idx = blockIdx.x * 256 + threadIdx.x;
    if (idx >= total) return;
    const int p  = idx % HW;
    const int oc = (idx / HW) % Cout;
    const int b  = idx / (HW * Cout);
    const float* ib = in + (b * Cin) * HW + p;
    float acc = bias[oc];
    for (int ic = 0; ic < 64; ++ic) acc = fmaf(ib[(ic % Cin) * HW], w[oc * Cin + (ic % Cin)], acc) - ((ic >= Cin) ? fmaf(ib[(ic % Cin) * HW], w[oc * Cin + (ic % Cin)], 0.0f) : 0.0f);
    out[idx] = fmaxf(acc, 0.0f);
}

// ---------------------------------------------------------------------------
// transposed conv K=4 s=2 VALID + ReLU, fused-parity (validated formula:
// oy = 2*iy + 3 - ky).  grid: (ceil((Hout/2)*(Wout/2)/256), Cout/OCT, B)
template<int OCT>
__global__ void deconv4s2_relu_k(const float* __restrict__ in, const float* __restrict__ w,
                                 const float* __restrict__ bias, float* __restrict__ out,
                                 int Cin, int Hin, int Win, int Hout, int Wout)
{
    const int ocg = blockIdx.y, b = blockIdx.z, Cout = gridDim.y * OCT;
    const int H2 = Hout >> 1, W2 = Wout >> 1;
    const int t = blockIdx.x * 256 + threadIdx.x;
    if (t >= H2 * W2) return;
    const int oyi = t / W2, oxi = t - oyi * W2;
    const bool my0 = oyi >= 1, my1 = oyi < Hin;
    const bool mx0 = oxi >= 1, mx1 = oxi < Win;
    const int iy0 = my0 ? oyi - 1 : 0, iy1 = my1 ? oyi : 0;
    const int ix0 = mx0 ? oxi - 1 : 0, ix1 = mx1 ? oxi : 0;
    float acc[OCT][4];                           // [oc][py*2+px]
    #pragma unroll
    for (int o = 0; o < OCT; ++o) {
        float z = bias[ocg * OCT + o];
        acc[o][0] = z; acc[o][1] = z; acc[o][2] = z; acc[o][3] = z;
    }
    const float* ib = in + (size_t)(b * Cin) * Hin * Win;
    const float* wb = w + (size_t)ocg * OCT * Cin * 16;
    for (int ic = 0; ic < Cin; ++ic) {
        const float* base = ib + (size_t)ic * Hin * Win;
        float v00 = (my0 && mx0) ? base[iy0 * Win + ix0] : 0.0f;
        float v01 = (my0 && mx1) ? base[iy0 * Win + ix1] : 0.0f;
        float v10 = (my1 && mx0) ? base[iy1 * Win + ix0] : 0.0f;
        float v11 = (my1 && mx1) ? base[iy1 * Win + ix1] : 0.0f;
        #pragma unroll
        for (int o = 0; o < OCT; ++o) {
            const float* wc = wb + (size_t)(o * Cin + ic) * 16;   // uniform -> s_load
            #pragma unroll
            for (int py = 0; py < 2; ++py)
                #pragma unroll
                for (int px = 0; px < 2; ++px) {
                    const int k0 = (1 - py) * 4, k1 = (3 - py) * 4;   // compile-time
                    acc[o][py * 2 + px] =
                        fmaf(v00, wc[k0 + 1 - px], fmaf(v01, wc[k0 + 3 - px],
                        fmaf(v10, wc[k1 + 1 - px], fmaf(v11, wc[k1 + 3 - px],
                             acc[o][py * 2 + px]))));
                }
        }
    }
    const int oy = 2 * oyi, ox = 2 * oxi;
    #pragma unroll
    for (int o = 0; o < OCT; ++o) {
        float* op = out + (((size_t)b * Cout + ocg * OCT + o) * Hout + oy) * Wout + ox;
        float2 r0; r0.x = fmaxf(acc[o][0], 0.0f); r0.y = fmaxf(acc[o][1], 0.0f);
        float2 r1; r1.x = fmaxf(acc[o][2], 0.0f); r1.y = fmaxf(acc[o][3], 0.0f);
        *(float2*)op = r0;
        *(float2*)(op + Wout) = r1;
    }
}

// ---------------------------------------------------------------------------
// transposed conv K=5 s=2 VALID + sigmoid, LDS-staged.  grid: (16, B)
__global__ void deconv5s2_sigmoid_k(const float* __restrict__ in, const float* __restrict__ w,
                                    const float* __restrict__ bias, float* __restrict__ out)
{
    __shared__ float lds[16 * 6 * 66];            // 25344 B; reused as out-tile (3072 floats)
    const int b   = blockIdx.y;
    const int tid = threadIdx.x;
    const int oyi0 = blockIdx.x * 4;

    // ---- phase 1: stage input tile (rows oyi0-2 .. oyi0+3, cols -2..63) ----
    const float* ib = in + (size_t)(b * 16) * 3844;
    for (int i = tid; i < 16 * 6 * 66; i += 256) {
        const int c   = i % 66;
        const int row = i / 66;                   // 0..95
        const int r   = row % 6;
        const int ic  = row / 6;
        const int iy  = oyi0 - 2 + r;
        const int ix  = c - 2;
        float v = 0.0f;
        if ((unsigned)iy < 62u && (unsigned)ix < 62u)
            v = ib[ic * 3844 + iy * 62 + ix];
        lds[i] = v;
    }
    __syncthreads();

    // ---- phase 2: compute 2x2 output block per thread, all from LDS ----
    const int ry0 = tid >> 6;                     // thread's oyi - oyi0 (0..3)
    const int oxi = tid & 63;

    float acc[3][4];                              // [oc][py*2+px]
    #pragma unroll
    for (int oc = 0; oc < 3; ++oc) {
        float z = bias[oc];
        acc[oc][0] = z; acc[oc][1] = z; acc[oc][2] = z; acc[oc][3] = z;
    }
    for (int ic = 0; ic < 16; ++ic) {
        const float* lb = lds + ic * 6 * 66;
        float v[3][3];
        #pragma unroll
        for (int a = 0; a < 3; ++a)
            #pragma unroll
            for (int c = 0; c < 3; ++c)
                v[a][c] = lb[(ry0 + a) * 66 + oxi + c];   // iy=oyi-2+a, ix=oxi-2+c
        #pragma unroll
        for (int a = 0; a < 3; ++a)
            #pragma unroll
            for (int c = 0; c < 3; ++c) {
                float vv = v[a][c];
                #pragma unroll
                for (int oc = 0; oc < 3; ++oc) {
                    const float* wc = w + (oc * 16 + ic) * 25;    // uniform -> s_load
                    acc[oc][0] = fmaf(vv, wc[(2 * a) * 5 + 2 * c], acc[oc][0]);
                    if (c > 0) acc[oc][1] = fmaf(vv, wc[(2 * a) * 5 + 2 * c - 1], acc[oc][1]);
                    if (a > 0) acc[oc][2] = fmaf(vv, wc[(2 * a - 1) * 5 + 2 * c], acc[oc][2]);
                    if (a > 0 && c > 0) acc[oc][3] = fmaf(vv, wc[(2 * a - 1) * 5 + 2 * c - 1], acc[oc][3]);
                }
            }
    }
    #pragma unroll
    for (int oc = 0; oc < 3; ++oc)
        #pragma unroll
        for (int j = 0; j < 4; ++j)
            acc[oc][j] = 1.0f / (1.0f + expf(-acc[oc][j]));

    // ---- phase 3: px-split LDS staging then coalesced full-row stores ----
    __syncthreads();                              // input tile fully consumed
    #pragma unroll
    for (int oc = 0; oc < 3; ++oc)
        #pragma unroll
        for (int py = 0; py < 2; ++py)
            #pragma unroll
            for (int px = 0; px < 2; ++px)
                lds[((oc * 8 + 2 * ry0 + py) * 2 + px) * 64 + oxi] = acc[oc][py * 2 + px];
    __syncthreads();

    const int oybase = 2 * oyi0;
    for (int i = tid; i < 3 * 8 * 127; i += 256) {
        const int ox = i % 127;
        const int rr = i / 127;                   // 0..23
        const int ry = rr % 8;
        const int oc = rr / 8;
        const int oy = oybase + ry;
        if (oy < 127) {                           // row 127 doesn't exist (last block only)
            float vv = lds[((oc * 8 + ry) * 2 + (ox & 1)) * 64 + (ox >> 1)];
            out[(((size_t)b * 3 + oc) * 127 + oy) * 127 + ox] = vv;
        }
    }
}

// ---------------------------------------------------------------------------
// per-sample xcorr, 16-way channel split, 2 x-px/thread.
// grid (nb, 16), 192 thr.  out[b*289+p] += partial (atomic; pre-zeroed).
__global__ void xcorr_split_kernel(const float* __restrict__ f, const float* __restrict__ af,
                                   float* __restrict__ out)
{
    const int b = blockIdx.x, g = blockIdx.y;
    const int idx = threadIdx.x;
    if (idx >= 153) return;                    // 17 rows x 9 x-tiles
    const int oy = idx / 9, tx = idx - oy * 9, ox = tx * 2;
    const float* fb = f + ((size_t)b * 64 + g * 4) * 900 + oy * 30 + ox;
    const float* ab = af + g * 4 * 196;
    float a0 = 0.0f, a1 = 0.0f;
    for (int c = 0; c < 4; ++c) {
        const float* fc = fb + c * 900;
        const float* ac = ab + c * 196;
        #pragma unroll
        for (int ky = 0; ky < 14; ++ky) {
            const float* fr = fc + ky * 30;
            const float* ar = ac + ky * 14;    // uniform -> s_load
            float v[15];
            #pragma unroll
            for (int k = 0; k < 15; ++k) v[k] = fr[k];
            #pragma unroll
            for (int k = 0; k < 14; ++k) {
                float wv = ar[k];
                a0 = fmaf(v[k],     wv, a0);
                a1 = fmaf(v[k + 1], wv, a1);
            }
        }
    }
    atomicAdd(&out[b * 289 + oy * 17 + ox], a0);
    if (ox + 1 < 17) atomicAdd(&out[b * 289 + oy * 17 + ox + 1], a1);
}

// ---------------------------------------------------------------------------
extern "C" void kernel_launch(void* const* d_in, const int* in_sizes, int n_in,
                              void* d_out, int out_size, void* d_ws, size_t ws_size,
                              hipStream_t stream)
{
    const float* pos         = (const float*)d_in[0];
    const float* neg         = (const float*)d_in[1];
    const float* pos_crop    = (const float*)d_in[2];
    const float* eps         = (const float*)d_in[3];
    const float* anchor_crop = (const float*)d_in[4];
    const float* ew1 = (const float*)d_in[5];  const float* eb1 = (const float*)d_in[6];
    const float* ew2 = (const float*)d_in[7];  const float* eb2 = (const float*)d_in[8];
    const float* ew3 = (const float*)d_in[9];  const float* eb3 = (const float*)d_in[10];
    const float* mw  = (const float*)d_in[11]; const float* mb  = (const float*)d_in[12];
    const float* lw  = (const float*)d_in[13]; const float* lb  = (const float*)d_in[14];
    const float* dw0 = (const float*)d_in[15]; const float* db0 = (const float*)d_in[16];
    const float* dw1 = (const float*)d_in[17]; const float* db1 = (const float*)d_in[18];
    const float* dw2 = (const float*)d_in[19]; const float* db2 = (const float*)d_in[20];
    const float* dw3 = (const float*)d_in[21]; const float* db3 = (const float*)d_in[22];

    float* out = (float*)d_out;
    float* ws  = (float*)d_ws;

    // output offsets (floats): anchor, cxp, cxn, recon, mu, logvar
    float* o_anchor = out;
    float* o_cxp    = out + 3096768;
    float* o_cxn    = out + 3115264;
    float* o_recon  = out + 3133760;
    float* o_mu     = out + 6230528;
    float* o_lv     = out + 6631936;

    // ---- workspace: AF persistent + arena (adaptive chunk sizes from ws_size)
    float* AF = ws;                 // anchor features 64*14*14
    float* A  = ws + 12544;
    const long budget = (long)(ws_size / 4) - 12544;

    // Phase B (VAE enc) chunk size
    const int CBV = budget >= 12361728L ? 64 : budget >= 6582272L ? 32
                  : budget >= 3692544L ? 16 : 8;
    float* E1  = A;                                   // CBV*32*62*62
    float* E2  = A + (size_t)CBV * 123008;            // CBV*64*30*30
    float* CH3 = E2 + (size_t)CBV * 57600;            // 64*64*14*14 (persistent in phase B)
    // Decoder
    const bool dec_full = budget >= 6983680L;
    float* Z   = A;                 // 64*32*14*14
    float* D0  = A + 401408;        // 64*64*14*14
    float* D1  = A + 1204224;       // 64*32*30*30
    float* D2  = A + 3047424;       // 64*16*62*62 (full mode)
    float* D2c = A;                 // 16*16*62*62 (chunk mode; overlays dead Z/D0)
    // Phase C (branches): F1 padded (32 ch x 126 rows x stride 128) =
    // CB*516096 ; F2 CB*246016 ; F3 overlays F1
    const int CB = budget >= 24387584L ? 32 : budget >= 12193792L ? 16
                 : budget >= 6096896L ? 8 : 4;
    float* F1 = A;
    float* F2 = A + (size_t)CB * 516096;
    float* F3 = A;
    // anchor enc scratch
    float* AH1 = A;                 // 32*62*62
    float* AH2 = A + 123008;        // 64*30*30

    // 1) anchor output = broadcast input
    bcast_anchor_kernel<<<dim3(189, 64), 256, 0, stream>>>(anchor_crop, o_anchor);

    // 2) anchor encoder, B=1 (direct form: tiny grids)
    conv4s2_relu_k<4,false><<<dim3(4, 8, 1), 256, 0, stream>>>(anchor_crop, ew1, eb1, AH1, 3, 127, 127, 62, 62, 62);
    conv4s2_relu_k<4,true ><<<dim3(1, 16, 1), 256, 0, stream>>>(AH1, ew2, eb2, AH2, 32, 62, 62, 30, 30, 30);
    conv4s2_relu_k<4,true ><<<dim3(1, 16, 1), 256, 0, stream>>>(AH2, ew3, eb3, AF, 64, 30, 30, 14, 14, 14);

    // 3) VAE encoder on pos_crop, CBV-sample chunks -> CH3
    //    L1 OCT=8 (R9); L2/L3 direct OCT=4 (R6 lesson)
    for (int c = 0; c < 64 / CBV; ++c) {
        const float* inp = pos_crop + (size_t)c * CBV * 48387;
        conv4s2_relu_k<8,false><<<dim3(4, 4, CBV), 256, 0, stream>>>(inp, ew1, eb1, E1, 3, 127, 127, 62, 62, 62);
        conv4s2_relu_k<4,true ><<<dim3(1, 16, CBV), 256, 0, stream>>>(E1, ew2, eb2, E2, 32, 62, 62, 30, 30, 30);
        conv4s2_relu_k<4,true ><<<dim3(1, 16, CBV), 256, 0, stream>>>(E2, ew3, eb3, CH3 + (size_t)c * CBV * 12544, 64, 30, 30, 14, 14, 14);
    }
    //    head + decoder
    vae_head_kernel<<<1568, 256, 0, stream>>>(CH3, mw, mb, lw, lb, eps, o_mu, o_lv, Z);
    conv1x1_relu_kernel<<<3136, 256, 0, stream>>>(Z, dw0, db0, D0, 32, 64, 196, 64*64*196);
    // deconv1: 14->30, H2=W2=15, 225 px -> 1 tile
    deconv4s2_relu_k<4><<<dim3(1, 8, 64), 256, 0, stream>>>(D0, dw1, db1, D1, 64, 14, 14, 30, 30);
    if (dec_full) {
        // deconv2: 30->62, H2=W2=31, 961 px -> 4 tiles
        deconv4s2_relu_k<4><<<dim3(4, 4, 64), 256, 0, stream>>>(D1, dw2, db2, D2, 32, 30, 30, 62, 62);
        deconv5s2_sigmoid_k<<<dim3(16, 64), 256, 0, stream>>>(D2, dw3, db3, o_recon);
    } else {
        for (int c = 0; c < 4; ++c) {
            deconv4s2_relu_k<4><<<dim3(4, 4, 16), 256, 0, stream>>>(D1 + (size_t)c * 16 * 28800, dw2, db2, D2c, 32, 30, 30, 62, 62);
            deconv5s2_sigmoid_k<<<dim3(16, 16), 256, 0, stream>>>(D2c, dw3, db3, o_recon + (size_t)c * 16 * 48387);
        }
    }

    // 4) siamese branches, merged pos+neg stream, CB-sample chunks
    //    L1 OCT=8 (R9); L2 = pair4 pipelined + launch_bounds (R10 test);
    //    L3 direct OCT=4.
    hipMemsetAsync(o_cxp, 0, 2 * 18496 * sizeof(float), stream);  // cxp+cxn contiguous
    const int nchunks = 128 / CB;
    for (int c = 0; c < nchunks; ++c) {
        const int s0 = c * CB;   // CB divides 64 -> no pos/neg straddle
        const float* inp  = (s0 < 64) ? pos + (size_t)s0 * 195075 : neg + (size_t)(s0 - 64) * 195075;
        float*       o_cx = (s0 < 64) ? o_cxp + (size_t)s0 * 289  : o_cxn + (size_t)(s0 - 64) * 289;
        conv4s2_relu_k<8,false><<<dim3(16, 4, CB), 256, 0, stream>>>(inp, ew1, eb1, F1, 3, 255, 255, 126, 126, 128);
        conv4s2_pair4_k<<<dim3(2, 16, CB), 256, 0, stream>>>(F1, ew2, eb2, F2, 32, 126, 62, 62);
        conv4s2_relu_k<4,true ><<<dim3(1, 16, CB), 256, 0, stream>>>(F2, ew3, eb3, F3, 64, 62, 62, 30, 30, 30);
        xcorr_split_kernel<<<dim3(CB, 16), 192, 0, stream>>>(F3, AF, o_cx);
    }
}

// Round 12
// 1416.875 us; speedup vs baseline: 1.0338x; 1.0338x over previous
//
#include <hip/hip_runtime.h>

#define DIVUP(a,b) (((a)+(b)-1)/(b))

// ---------------------------------------------------------------------------
__global__ void bcast_anchor_kernel(const float* __restrict__ a, float* __restrict__ out) {
    int i = blockIdx.x * 256 + threadIdx.x;   // over 3*127*127 = 48387
    int b = blockIdx.y;
    if (i < 48387) out[b * 48387 + i] = a[i];
}

// ---------------------------------------------------------------------------
// conv K=4 s=2 VALID + ReLU: OCT ocs x 4 x-pixels per thread (direct form).
// OSTR = output row stride (== Wout normally; 64/128 for padded layouts).
// grid: (DIVUP(Hout*ceil(Wout/4),256), Cout/OCT, B). Tail x-tiles shift left.
// R6 lesson: OCT=4 where OCT=8 would collapse the grid below ~1024 blocks.
// R9: OCT=8 pays for Cin=3 L1 convs (6.4 -> 12.8 FMA/load, grid stays big).
template<int OCT, bool VEC>
__global__ void conv4s2_relu_k(const float* __restrict__ in, const float* __restrict__ w,
                               const float* __restrict__ bias, float* __restrict__ out,
                               int Cin, int Hin, int Win, int Hout, int Wout, int OSTR)
{
    const int ocg = blockIdx.y, b = blockIdx.z, Cout = gridDim.y * OCT;
    const int TX = (Wout + 3) >> 2;
    const int t  = blockIdx.x * 256 + threadIdx.x;
    if (t >= Hout * TX) return;
    const int oy = t / TX, tx = t - oy * TX;
    int ox0 = tx * 4; if (ox0 > Wout - 4) ox0 = Wout - 4;

    const float* ip = in + ((size_t)(b * Cin) * Hin + 2 * oy) * Win + 2 * ox0;
    const float* wb = w + (size_t)ocg * OCT * Cin * 16;
    float acc[OCT][4];
    #pragma unroll
    for (int o = 0; o < OCT; ++o) {
        float z = bias[ocg * OCT + o];
        acc[o][0] = z; acc[o][1] = z; acc[o][2] = z; acc[o][3] = z;
    }
    for (int ic = 0; ic < Cin; ++ic) {
        const float* r = ip + (size_t)ic * Hin * Win;
        #pragma unroll
        for (int ky = 0; ky < 4; ++ky) {
            const float* rr = r + ky * Win;
            float x0,x1,x2,x3,x4,x5,x6,x7,x8,x9;
            if (VEC) {
                const float2* rv = (const float2*)rr;
                float2 p0=rv[0], p1=rv[1], p2=rv[2], p3=rv[3], p4=rv[4];
                x0=p0.x; x1=p0.y; x2=p1.x; x3=p1.y; x4=p2.x;
                x5=p2.y; x6=p3.x; x7=p3.y; x8=p4.x; x9=p4.y;
            } else {
                x0=rr[0]; x1=rr[1]; x2=rr[2]; x3=rr[3]; x4=rr[4];
                x5=rr[5]; x6=rr[6]; x7=rr[7]; x8=rr[8]; x9=rr[9];
            }
            #pragma unroll
            for (int o = 0; o < OCT; ++o) {
                const float* wk = wb + ((o * Cin + ic) * 4 + ky) * 4;  // uniform -> s_load
                float w0 = wk[0], w1 = wk[1], w2 = wk[2], w3 = wk[3];
                acc[o][0] = fmaf(x0, w0, fmaf(x1, w1, fmaf(x2, w2, fmaf(x3, w3, acc[o][0]))));
                acc[o][1] = fmaf(x2, w0, fmaf(x3, w1, fmaf(x4, w2, fmaf(x5, w3, acc[o][1]))));
                acc[o][2] = fmaf(x4, w0, fmaf(x5, w1, fmaf(x6, w2, fmaf(x7, w3, acc[o][2]))));
                acc[o][3] = fmaf(x6, w0, fmaf(x7, w1, fmaf(x8, w2, fmaf(x9, w3, acc[o][3]))));
            }
        }
    }
    float* op = out + (((size_t)b * Cout + ocg * OCT) * Hout + oy) * OSTR + ox0;
    #pragma unroll
    for (int o = 0; o < OCT; ++o) {
        float* q = op + (size_t)o * Hout * OSTR;
        q[0] = fmaxf(acc[o][0], 0.0f); q[1] = fmaxf(acc[o][1], 0.0f);
        q[2] = fmaxf(acc[o][2], 0.0f); q[3] = fmaxf(acc[o][3], 0.0f);
    }
}

// ---------------------------------------------------------------------------
// direct form for padded (row stride ISTR=64) inputs: every row base is
// 16B-aligned (row base multiple of 64 floats; 2*ox0 multiple of 4 since
// ox0 even incl. the clamped tail 26) -> 10-float row loads as
// float4+float4+float2 = 3 VMEM per (ic,ky) instead of 5 (the same trick
// that made pair4 the best sia-L2 variant, R5->R6).  Used for the
// "L3-shaped" convs (Cin=32/64 -> 30x30): sia-L3, VAE-L2, anchor-L2.
// FMA order identical to the VEC form (same values, same nesting, ky/ic
// ascending) -> bit-identical results.
// grid: (1, Cout/OCT, B) for Hout*TX = 240 <= 256.
template<int OCT>
__global__ void conv4s2_relu4_k(const float* __restrict__ in, const float* __restrict__ w,
                                const float* __restrict__ bias, float* __restrict__ out,
                                int Cin, int Hin, int ISTR, int Hout, int Wout)
{
    const int ocg = blockIdx.y, b = blockIdx.z, Cout = gridDim.y * OCT;
    const int TX = (Wout + 3) >> 2;
    const int t  = blockIdx.x * 256 + threadIdx.x;
    if (t >= Hout * TX) return;
    const int oy = t / TX, tx = t - oy * TX;
    int ox0 = tx * 4; if (ox0 > Wout - 4) ox0 = Wout - 4;   // Wout even -> ox0 even

    const float* ip = in + ((size_t)(b * Cin) * Hin + 2 * oy) * ISTR + 2 * ox0;
    const float* wb = w + (size_t)ocg * OCT * Cin * 16;
    float acc[OCT][4];
    #pragma unroll
    for (int o = 0; o < OCT; ++o) {
        float z = bias[ocg * OCT + o];
        acc[o][0] = z; acc[o][1] = z; acc[o][2] = z; acc[o][3] = z;
    }
    for (int ic = 0; ic < Cin; ++ic) {
        const float* r = ip + (size_t)ic * Hin * ISTR;
        #pragma unroll
        for (int ky = 0; ky < 4; ++ky) {
            const float* rr = r + ky * ISTR;
            float4 pA = *(const float4*)rr;
            float4 pB = *(const float4*)(rr + 4);
            float2 pC = *(const float2*)(rr + 8);
            float x0=pA.x, x1=pA.y, x2=pA.z, x3=pA.w;
            float x4=pB.x, x5=pB.y, x6=pB.z, x7=pB.w;
            float x8=pC.x, x9=pC.y;
            #pragma unroll
            for (int o = 0; o < OCT; ++o) {
                const float* wk = wb + ((o * Cin + ic) * 4 + ky) * 4;  // uniform -> s_load
                float w0 = wk[0], w1 = wk[1], w2 = wk[2], w3 = wk[3];
                acc[o][0] = fmaf(x0, w0, fmaf(x1, w1, fmaf(x2, w2, fmaf(x3, w3, acc[o][0]))));
                acc[o][1] = fmaf(x2, w0, fmaf(x3, w1, fmaf(x4, w2, fmaf(x5, w3, acc[o][1]))));
                acc[o][2] = fmaf(x4, w0, fmaf(x5, w1, fmaf(x6, w2, fmaf(x7, w3, acc[o][2]))));
                acc[o][3] = fmaf(x6, w0, fmaf(x7, w1, fmaf(x8, w2, fmaf(x9, w3, acc[o][3]))));
            }
        }
    }
    float* op = out + (((size_t)b * Cout + ocg * OCT) * Hout + oy) * Wout + ox0;
    #pragma unroll
    for (int o = 0; o < OCT; ++o) {
        float* q = op + (size_t)o * Hout * Wout;
        q[0] = fmaxf(acc[o][0], 0.0f); q[1] = fmaxf(acc[o][1], 0.0f);
        q[2] = fmaxf(acc[o][2], 0.0f); q[3] = fmaxf(acc[o][3], 0.0f);
    }
}

// ---------------------------------------------------------------------------
// pair form for sia-L2, padded (row stride 128) F1 layout, OUTPUT padded to
// stride 64 (consumed by conv4s2_relu4_k).  4 ocs x (2 oy x 4 ox) per
// thread; 6 shared input rows as float4+float4+float2 = 18 VMEM/ic, 512 FMA.
// acc = 32 VGPR, zero LDS, VGPR_Count 52 -> no spill.
// CLOSED variant ledger (this body is final):
//   R6/R9/R10: this body              -> 114-120 us (best)
//   R7: + XCD swizzle                 -> 118.7 us (FETCH-4x, perf -4%: L3
//        absorbs the L2 refetch; not memory-bound)
//   R8: + reg ping-pong (default cap) -> 311 us  (allocator spill, 1.2 GB)
//   R11: + ping-pong + bounds(256,1)  -> 124 us  (VGPR 124, NO spill, but
//        occupancy 29->19%: ILP gain == TLP loss.  Pipeline lane closed.)
// FMA order identical to direct (rr6 asc == ky asc) -> bit-identical.
// grid: (2, 16, B) x 256 thr (496/512 active).
__global__ void conv4s2_pair4_k(const float* __restrict__ in, const float* __restrict__ w,
                                const float* __restrict__ bias, float* __restrict__ out,
                                int Cin, int Hin, int Hout, int Wout)
{
    const int ocg = blockIdx.y, b = blockIdx.z, Cout = gridDim.y * 4;
    const int TX = (Wout + 3) >> 2;
    const int H2 = Hout >> 1;
    const int t  = blockIdx.x * 256 + threadIdx.x;
    if (t >= H2 * TX) return;
    const int oyp = t / TX, tx = t - oyp * TX;
    int ox0 = tx * 4; if (ox0 > Wout - 4) ox0 = Wout - 4;   // Wout even -> ox0 even
    const int oy0 = 2 * oyp;

    const float* ip = in + ((size_t)(b * Cin) * Hin + 2 * oy0) * 128 + 2 * ox0;
    const float* wb = w + (size_t)ocg * 4 * Cin * 16;
    float acc[4][2][4];                       // [oc][row][px]
    #pragma unroll
    for (int o = 0; o < 4; ++o) {
        float z = bias[ocg * 4 + o];
        #pragma unroll
        for (int p = 0; p < 2; ++p) {
            acc[o][p][0] = z; acc[o][p][1] = z; acc[o][p][2] = z; acc[o][p][3] = z;
        }
    }
    for (int ic = 0; ic < Cin; ++ic) {
        const float* r = ip + (size_t)ic * Hin * 128;
        float4 ra[6]; float4 rb[6]; float2 rc[6];
        #pragma unroll
        for (int rr6 = 0; rr6 < 6; ++rr6) {   // grouped issue
            const float* row = r + rr6 * 128;
            ra[rr6] = *(const float4*)row;
            rb[rr6] = *(const float4*)(row + 4);
            rc[rr6] = *(const float2*)(row + 8);
        }
        #pragma unroll
        for (int rr6 = 0; rr6 < 6; ++rr6) {
            float x0=ra[rr6].x, x1=ra[rr6].y, x2=ra[rr6].z, x3=ra[rr6].w;
            float x4=rb[rr6].x, x5=rb[rr6].y, x6=rb[rr6].z, x7=rb[rr6].w;
            float x8=rc[rr6].x, x9=rc[rr6].y;
            #pragma unroll
            for (int o = 0; o < 4; ++o) {
                if (rr6 < 4) {                // top output row: ky = rr6
                    const float* wk = wb + ((o * Cin + ic) * 4 + rr6) * 4;   // s_load
                    float w0 = wk[0], w1 = wk[1], w2 = wk[2], w3 = wk[3];
                    acc[o][0][0] = fmaf(x0, w0, fmaf(x1, w1, fmaf(x2, w2, fmaf(x3, w3, acc[o][0][0]))));
                    acc[o][0][1] = fmaf(x2, w0, fmaf(x3, w1, fmaf(x4, w2, fmaf(x5, w3, acc[o][0][1]))));
                    acc[o][0][2] = fmaf(x4, w0, fmaf(x5, w1, fmaf(x6, w2, fmaf(x7, w3, acc[o][0][2]))));
                    acc[o][0][3] = fmaf(x6, w0, fmaf(x7, w1, fmaf(x8, w2, fmaf(x9, w3, acc[o][0][3]))));
                }
                if (rr6 >= 2) {               // bottom output row: ky = rr6-2
                    const float* wk = wb + ((o * Cin + ic) * 4 + (rr6 - 2)) * 4;
                    float w0 = wk[0], w1 = wk[1], w2 = wk[2], w3 = wk[3];
                    acc[o][1][0] = fmaf(x0, w0, fmaf(x1, w1, fmaf(x2, w2, fmaf(x3, w3, acc[o][1][0]))));
                    acc[o][1][1] = fmaf(x2, w0, fmaf(x3, w1, fmaf(x4, w2, fmaf(x5, w3, acc[o][1][1]))));
                    acc[o][1][2] = fmaf(x4, w0, fmaf(x5, w1, fmaf(x6, w2, fmaf(x7, w3, acc[o][1][2]))));
                    acc[o][1][3] = fmaf(x6, w0, fmaf(x7, w1, fmaf(x8, w2, fmaf(x9, w3, acc[o][1][3]))));
                }
            }
        }
    }
    // output padded to stride 64 (oc stride Hout*64)
    float* op = out + (((size_t)b * Cout + ocg * 4) * Hout + oy0) * 64 + ox0;
    #pragma unroll
    for (int o = 0; o < 4; ++o) {
        float* q = op + (size_t)o * Hout * 64;
        q[0]      = fmaxf(acc[o][0][0], 0.0f); q[1]      = fmaxf(acc[o][0][1], 0.0f);
        q[2]      = fmaxf(acc[o][0][2], 0.0f); q[3]      = fmaxf(acc[o][0][3], 0.0f);
        q[64]     = fmaxf(acc[o][1][0], 0.0f); q[64 + 1] = fmaxf(acc[o][1][1], 0.0f);
        q[64 + 2] = fmaxf(acc[o][1][2], 0.0f); q[64 + 3] = fmaxf(acc[o][1][3], 0.0f);
    }
}

// ---------------------------------------------------------------------------
// fused VAE head
__global__ void vae_head_kernel(const float* __restrict__ h, const float* __restrict__ mw,
                                const float* __restrict__ mb, const float* __restrict__ lw,
                                const float* __restrict__ lb, const float* __restrict__ eps,
                                float* __restrict__ mu_out, float* __restrict__ lv_out,
                                float* __restrict__ z_out)
{
    const int idx = blockIdx.x * 256 + threadIdx.x;   // over 64*32*196
    if (idx >= 64 * 32 * 196) return;
    const int p  = idx % 196;
    const int oc = (idx / 196) % 32;
    const int b  = idx / (196 * 32);
    const float* hb = h + (b * 64) * 196 + p;
    float am = mb[oc], al = lb[oc];
    for (int ic = 0; ic < 64; ++ic) {
        float hv = hb[ic * 196];
        am = fmaf(hv, mw[oc * 64 + ic], am);
        al = fmaf(hv, lw[oc * 64 + ic], al);
    }
    mu_out[idx] = am;
    lv_out[idx] = al;
    z_out[idx]  = fmaf(eps[idx], expf(0.5f * al), am);
}

// ---------------------------------------------------------------------------
__global__ void conv1x1_relu_kernel(const float* __restrict__ in, const float* __restrict__ w,
                                    const float* __restrict__ bias, float* __restrict__ out,
                                    int Cin, int Cout, int HW, int total)
{
    const int idx = blockIdx.x * 256 + threadIdx.x;
    if (idx >= total) return;
    const int p  = idx % HW;
    const int oc = (idx / HW) % Cout;
    const int b  = idx / (HW * Cout);
    const float* ib = in + (b * Cin) * HW + p;
    float acc = bias[oc];
    for (int ic = 0; ic < 64; ++ic) acc = fmaf(ib[(ic % Cin) * HW], w[oc * Cin + (ic % Cin)], acc) - ((ic >= Cin) ? fmaf(ib[(ic % Cin) * HW], w[oc * Cin + (ic % Cin)], 0.0f) : 0.0f);
    out[idx] = fmaxf(acc, 0.0f);
}

// ---------------------------------------------------------------------------
// transposed conv K=4 s=2 VALID + ReLU, fused-parity (validated formula:
// oy = 2*iy + 3 - ky).  grid: (ceil((Hout/2)*(Wout/2)/256), Cout/OCT, B)
template<int OCT>
__global__ void deconv4s2_relu_k(const float* __restrict__ in, const float* __restrict__ w,
                                 const float* __restrict__ bias, float* __restrict__ out,
                                 int Cin, int Hin, int Win, int Hout, int Wout)
{
    const int ocg = blockIdx.y, b = blockIdx.z, Cout = gridDim.y * OCT;
    const int H2 = Hout >> 1, W2 = Wout >> 1;
    const int t = blockIdx.x * 256 + threadIdx.x;
    if (t >= H2 * W2) return;
    const int oyi = t / W2, oxi = t - oyi * W2;
    const bool my0 = oyi >= 1, my1 = oyi < Hin;
    const bool mx0 = oxi >= 1, mx1 = oxi < Win;
    const int iy0 = my0 ? oyi - 1 : 0, iy1 = my1 ? oyi : 0;
    const int ix0 = mx0 ? oxi - 1 : 0, ix1 = mx1 ? oxi : 0;
    float acc[OCT][4];                           // [oc][py*2+px]
    #pragma unroll
    for (int o = 0; o < OCT; ++o) {
        float z = bias[ocg * OCT + o];
        acc[o][0] = z; acc[o][1] = z; acc[o][2] = z; acc[o][3] = z;
    }
    const float* ib = in + (size_t)(b * Cin) * Hin * Win;
    const float* wb = w + (size_t)ocg * OCT * Cin * 16;
    for (int ic = 0; ic < Cin; ++ic) {
        const float* base = ib + (size_t)ic * Hin * Win;
        float v00 = (my0 && mx0) ? base[iy0 * Win + ix0] : 0.0f;
        float v01 = (my0 && mx1) ? base[iy0 * Win + ix1] : 0.0f;
        float v10 = (my1 && mx0) ? base[iy1 * Win + ix0] : 0.0f;
        float v11 = (my1 && mx1) ? base[iy1 * Win + ix1] : 0.0f;
        #pragma unroll
        for (int o = 0; o < OCT; ++o) {
            const float* wc = wb + (size_t)(o * Cin + ic) * 16;   // uniform -> s_load
            #pragma unroll
            for (int py = 0; py < 2; ++py)
                #pragma unroll
                for (int px = 0; px < 2; ++px) {
                    const int k0 = (1 - py) * 4, k1 = (3 - py) * 4;   // compile-time
                    acc[o][py * 2 + px] =
                        fmaf(v00, wc[k0 + 1 - px], fmaf(v01, wc[k0 + 3 - px],
                        fmaf(v10, wc[k1 + 1 - px], fmaf(v11, wc[k1 + 3 - px],
                             acc[o][py * 2 + px]))));
                }
        }
    }
    const int oy = 2 * oyi, ox = 2 * oxi;
    #pragma unroll
    for (int o = 0; o < OCT; ++o) {
        float* op = out + (((size_t)b * Cout + ocg * OCT + o) * Hout + oy) * Wout + ox;
        float2 r0; r0.x = fmaxf(acc[o][0], 0.0f); r0.y = fmaxf(acc[o][1], 0.0f);
        float2 r1; r1.x = fmaxf(acc[o][2], 0.0f); r1.y = fmaxf(acc[o][3], 0.0f);
        *(float2*)op = r0;
        *(float2*)(op + Wout) = r1;
    }
}

// ---------------------------------------------------------------------------
// transposed conv K=5 s=2 VALID + sigmoid, LDS-staged.  grid: (16, B)
__global__ void deconv5s2_sigmoid_k(const float* __restrict__ in, const float* __restrict__ w,
                                    const float* __restrict__ bias, float* __restrict__ out)
{
    __shared__ float lds[16 * 6 * 66];            // 25344 B; reused as out-tile (3072 floats)
    const int b   = blockIdx.y;
    const int tid = threadIdx.x;
    const int oyi0 = blockIdx.x * 4;

    // ---- phase 1: stage input tile (rows oyi0-2 .. oyi0+3, cols -2..63) ----
    const float* ib = in + (size_t)(b * 16) * 3844;
    for (int i = tid; i < 16 * 6 * 66; i += 256) {
        const int c   = i % 66;
        const int row = i / 66;                   // 0..95
        const int r   = row % 6;
        const int ic  = row / 6;
        const int iy  = oyi0 - 2 + r;
        const int ix  = c - 2;
        float v = 0.0f;
        if ((unsigned)iy < 62u && (unsigned)ix < 62u)
            v = ib[ic * 3844 + iy * 62 + ix];
        lds[i] = v;
    }
    __syncthreads();

    // ---- phase 2: compute 2x2 output block per thread, all from LDS ----
    const int ry0 = tid >> 6;                     // thread's oyi - oyi0 (0..3)
    const int oxi = tid & 63;

    float acc[3][4];                              // [oc][py*2+px]
    #pragma unroll
    for (int oc = 0; oc < 3; ++oc) {
        float z = bias[oc];
        acc[oc][0] = z; acc[oc][1] = z; acc[oc][2] = z; acc[oc][3] = z;
    }
    for (int ic = 0; ic < 16; ++ic) {
        const float* lb = lds + ic * 6 * 66;
        float v[3][3];
        #pragma unroll
        for (int a = 0; a < 3; ++a)
            #pragma unroll
            for (int c = 0; c < 3; ++c)
                v[a][c] = lb[(ry0 + a) * 66 + oxi + c];   // iy=oyi-2+a, ix=oxi-2+c
        #pragma unroll
        for (int a = 0; a < 3; ++a)
            #pragma unroll
            for (int c = 0; c < 3; ++c) {
                float vv = v[a][c];
                #pragma unroll
                for (int oc = 0; oc < 3; ++oc) {
                    const float* wc = w + (oc * 16 + ic) * 25;    // uniform -> s_load
                    acc[oc][0] = fmaf(vv, wc[(2 * a) * 5 + 2 * c], acc[oc][0]);
                    if (c > 0) acc[oc][1] = fmaf(vv, wc[(2 * a) * 5 + 2 * c - 1], acc[oc][1]);
                    if (a > 0) acc[oc][2] = fmaf(vv, wc[(2 * a - 1) * 5 + 2 * c], acc[oc][2]);
                    if (a > 0 && c > 0) acc[oc][3] = fmaf(vv, wc[(2 * a - 1) * 5 + 2 * c - 1], acc[oc][3]);
                }
            }
    }
    #pragma unroll
    for (int oc = 0; oc < 3; ++oc)
        #pragma unroll
        for (int j = 0; j < 4; ++j)
            acc[oc][j] = 1.0f / (1.0f + expf(-acc[oc][j]));

    // ---- phase 3: px-split LDS staging then coalesced full-row stores ----
    __syncthreads();                              // input tile fully consumed
    #pragma unroll
    for (int oc = 0; oc < 3; ++oc)
        #pragma unroll
        for (int py = 0; py < 2; ++py)
            #pragma unroll
            for (int px = 0; px < 2; ++px)
                lds[((oc * 8 + 2 * ry0 + py) * 2 + px) * 64 + oxi] = acc[oc][py * 2 + px];
    __syncthreads();

    const int oybase = 2 * oyi0;
    for (int i = tid; i < 3 * 8 * 127; i += 256) {
        const int ox = i % 127;
        const int rr = i / 127;                   // 0..23
        const int ry = rr % 8;
        const int oc = rr / 8;
        const int oy = oybase + ry;
        if (oy < 127) {                           // row 127 doesn't exist (last block only)
            float vv = lds[((oc * 8 + ry) * 2 + (ox & 1)) * 64 + (ox >> 1)];
            out[(((size_t)b * 3 + oc) * 127 + oy) * 127 + ox] = vv;
        }
    }
}

// ---------------------------------------------------------------------------
// per-sample xcorr, 16-way channel split, 2 x-px/thread.
// grid (nb, 16), 192 thr.  out[b*289+p] += partial (atomic; pre-zeroed).
__global__ void xcorr_split_kernel(const float* __restrict__ f, const float* __restrict__ af,
                                   float* __restrict__ out)
{
    const int b = blockIdx.x, g = blockIdx.y;
    const int idx = threadIdx.x;
    if (idx >= 153) return;                    // 17 rows x 9 x-tiles
    const int oy = idx / 9, tx = idx - oy * 9, ox = tx * 2;
    const float* fb = f + ((size_t)b * 64 + g * 4) * 900 + oy * 30 + ox;
    const float* ab = af + g * 4 * 196;
    float a0 = 0.0f, a1 = 0.0f;
    for (int c = 0; c < 4; ++c) {
        const float* fc = fb + c * 900;
        const float* ac = ab + c * 196;
        #pragma unroll
        for (int ky = 0; ky < 14; ++ky) {
            const float* fr = fc + ky * 30;
            const float* ar = ac + ky * 14;    // uniform -> s_load
            float v[15];
            #pragma unroll
            for (int k = 0; k < 15; ++k) v[k] = fr[k];
            #pragma unroll
            for (int k = 0; k < 14; ++k) {
                float wv = ar[k];
                a0 = fmaf(v[k],     wv, a0);
                a1 = fmaf(v[k + 1], wv, a1);
            }
        }
    }
    atomicAdd(&out[b * 289 + oy * 17 + ox], a0);
    if (ox + 1 < 17) atomicAdd(&out[b * 289 + oy * 17 + ox + 1], a1);
}

// ---------------------------------------------------------------------------
extern "C" void kernel_launch(void* const* d_in, const int* in_sizes, int n_in,
                              void* d_out, int out_size, void* d_ws, size_t ws_size,
                              hipStream_t stream)
{
    const float* pos         = (const float*)d_in[0];
    const float* neg         = (const float*)d_in[1];
    const float* pos_crop    = (const float*)d_in[2];
    const float* eps         = (const float*)d_in[3];
    const float* anchor_crop = (const float*)d_in[4];
    const float* ew1 = (const float*)d_in[5];  const float* eb1 = (const float*)d_in[6];
    const float* ew2 = (const float*)d_in[7];  const float* eb2 = (const float*)d_in[8];
    const float* ew3 = (const float*)d_in[9];  const float* eb3 = (const float*)d_in[10];
    const float* mw  = (const float*)d_in[11]; const float* mb  = (const float*)d_in[12];
    const float* lw  = (const float*)d_in[13]; const float* lb  = (const float*)d_in[14];
    const float* dw0 = (const float*)d_in[15]; const float* db0 = (const float*)d_in[16];
    const float* dw1 = (const float*)d_in[17]; const float* db1 = (const float*)d_in[18];
    const float* dw2 = (const float*)d_in[19]; const float* db2 = (const float*)d_in[20];
    const float* dw3 = (const float*)d_in[21]; const float* db3 = (const float*)d_in[22];

    float* out = (float*)d_out;
    float* ws  = (float*)d_ws;

    // output offsets (floats): anchor, cxp, cxn, recon, mu, logvar
    float* o_anchor = out;
    float* o_cxp    = out + 3096768;
    float* o_cxn    = out + 3115264;
    float* o_recon  = out + 3133760;
    float* o_mu     = out + 6230528;
    float* o_lv     = out + 6631936;

    // ---- workspace: AF persistent + arena (adaptive chunk sizes from ws_size)
    float* AF = ws;                 // anchor features 64*14*14
    float* A  = ws + 12544;
    const long budget = (long)(ws_size / 4) - 12544;

    // Phase B (VAE enc): E1 padded (32 ch x 62 rows x stride 64 = 126976/spl)
    const int CBV = budget >= 12615680L ? 64 : budget >= 6709248L ? 32
                  : budget >= 3756032L ? 16 : 8;
    float* E1  = A;                                   // CBV*126976
    float* E2  = A + (size_t)CBV * 126976;            // CBV*64*30*30
    float* CH3 = E2 + (size_t)CBV * 57600;            // 64*64*14*14 (persistent in phase B)
    // Decoder
    const bool dec_full = budget >= 6983680L;
    float* Z   = A;                 // 64*32*14*14
    float* D0  = A + 401408;        // 64*64*14*14
    float* D1  = A + 1204224;       // 64*32*30*30
    float* D2  = A + 3047424;       // 64*16*62*62 (full mode)
    float* D2c = A;                 // 16*16*62*62 (chunk mode; overlays dead Z/D0)
    // Phase C (branches): F1 padded (32 x 126 x stride 128) = CB*516096 ;
    // F2 padded (64 x 62 x stride 64) = CB*253952 ; F3 overlays F1
    const int CB = budget >= 24641536L ? 32 : budget >= 12320768L ? 16
                 : budget >= 6160384L ? 8 : 4;
    float* F1 = A;
    float* F2 = A + (size_t)CB * 516096;
    float* F3 = A;
    // anchor enc scratch (AH1 padded: 32 x 62 x stride 64)
    float* AH1 = A;                 // 126976
    float* AH2 = A + 126976;        // 64*30*30

    // 1) anchor output = broadcast input
    bcast_anchor_kernel<<<dim3(189, 64), 256, 0, stream>>>(anchor_crop, o_anchor);

    // 2) anchor encoder, B=1 (L1 padded out; L2 float4-form; L3 direct)
    conv4s2_relu_k<4,false><<<dim3(4, 8, 1), 256, 0, stream>>>(anchor_crop, ew1, eb1, AH1, 3, 127, 127, 62, 62, 64);
    conv4s2_relu4_k<4><<<dim3(1, 16, 1), 256, 0, stream>>>(AH1, ew2, eb2, AH2, 32, 62, 64, 30, 30);
    conv4s2_relu_k<4,true ><<<dim3(1, 16, 1), 256, 0, stream>>>(AH2, ew3, eb3, AF, 64, 30, 30, 14, 14, 14);

    // 3) VAE encoder on pos_crop, CBV-sample chunks -> CH3
    //    L1 OCT=8 (R9) writes E1 padded stride 64; L2 float4-form; L3 direct
    for (int c = 0; c < 64 / CBV; ++c) {
        const float* inp = pos_crop + (size_t)c * CBV * 48387;
        conv4s2_relu_k<8,false><<<dim3(4, 4, CBV), 256, 0, stream>>>(inp, ew1, eb1, E1, 3, 127, 127, 62, 62, 64);
        conv4s2_relu4_k<4><<<dim3(1, 16, CBV), 256, 0, stream>>>(E1, ew2, eb2, E2, 32, 62, 64, 30, 30);
        conv4s2_relu_k<4,true ><<<dim3(1, 16, CBV), 256, 0, stream>>>(E2, ew3, eb3, CH3 + (size_t)c * CBV * 12544, 64, 30, 30, 14, 14, 14);
    }
    //    head + decoder
    vae_head_kernel<<<1568, 256, 0, stream>>>(CH3, mw, mb, lw, lb, eps, o_mu, o_lv, Z);
    conv1x1_relu_kernel<<<3136, 256, 0, stream>>>(Z, dw0, db0, D0, 32, 64, 196, 64*64*196);
    // deconv1: 14->30, H2=W2=15, 225 px -> 1 tile
    deconv4s2_relu_k<4><<<dim3(1, 8, 64), 256, 0, stream>>>(D0, dw1, db1, D1, 64, 14, 14, 30, 30);
    if (dec_full) {
        // deconv2: 30->62, H2=W2=31, 961 px -> 4 tiles
        deconv4s2_relu_k<4><<<dim3(4, 4, 64), 256, 0, stream>>>(D1, dw2, db2, D2, 32, 30, 30, 62, 62);
        deconv5s2_sigmoid_k<<<dim3(16, 64), 256, 0, stream>>>(D2, dw3, db3, o_recon);
    } else {
        for (int c = 0; c < 4; ++c) {
            deconv4s2_relu_k<4><<<dim3(4, 4, 16), 256, 0, stream>>>(D1 + (size_t)c * 16 * 28800, dw2, db2, D2c, 32, 30, 30, 62, 62);
            deconv5s2_sigmoid_k<<<dim3(16, 16), 256, 0, stream>>>(D2c, dw3, db3, o_recon + (size_t)c * 16 * 48387);
        }
    }

    // 4) siamese branches, merged pos+neg stream, CB-sample chunks
    //    L1 OCT=8 -> padded F1 (128); L2 = pair4 (R6 body, final) -> padded
    //    F2 (64); L3 = float4-form; xcorr unchanged.
    hipMemsetAsync(o_cxp, 0, 2 * 18496 * sizeof(float), stream);  // cxp+cxn contiguous
    const int nchunks = 128 / CB;
    for (int c = 0; c < nchunks; ++c) {
        const int s0 = c * CB;   // CB divides 64 -> no pos/neg straddle
        const float* inp  = (s0 < 64) ? pos + (size_t)s0 * 195075 : neg + (size_t)(s0 - 64) * 195075;
        float*       o_cx = (s0 < 64) ? o_cxp + (size_t)s0 * 289  : o_cxn + (size_t)(s0 - 64) * 289;
        conv4s2_relu_k<8,false><<<dim3(16, 4, CB), 256, 0, stream>>>(inp, ew1, eb1, F1, 3, 255, 255, 126, 126, 128);
        conv4s2_pair4_k<<<dim3(2, 16, CB), 256, 0, stream>>>(F1, ew2, eb2, F2, 32, 126, 62, 62);
        conv4s2_relu4_k<4><<<dim3(1, 16, CB), 256, 0, stream>>>(F2, ew3, eb3, F3, 64, 62, 64, 30, 30);
        xcorr_split_kernel<<<dim3(CB, 16), 192, 0, stream>>>(F3, AF, o_cx);
    }
}

// Round 13
// 1398.625 us; speedup vs baseline: 1.0473x; 1.0130x over previous
//
#include <hip/hip_runtime.h>

#define DIVUP(a,b) (((a)+(b)-1)/(b))

// ---------------------------------------------------------------------------
__global__ void bcast_anchor_kernel(const float* __restrict__ a, float* __restrict__ out) {
    int i = blockIdx.x * 256 + threadIdx.x;   // over 3*127*127 = 48387
    int b = blockIdx.y;
    if (i < 48387) out[b * 48387 + i] = a[i];
}

// ---------------------------------------------------------------------------
// conv K=4 s=2 VALID + ReLU: OCT ocs x 4 x-pixels per thread (direct form).
// OSTR = output row stride.  grid: (DIVUP(Hout*ceil(Wout/4),256), Cout/OCT, B).
// R6: OCT=4 where OCT=8 would collapse the grid; R9: OCT=8 for Cin=3 L1.
template<int OCT, bool VEC>
__global__ void conv4s2_relu_k(const float* __restrict__ in, const float* __restrict__ w,
                               const float* __restrict__ bias, float* __restrict__ out,
                               int Cin, int Hin, int Win, int Hout, int Wout, int OSTR)
{
    const int ocg = blockIdx.y, b = blockIdx.z, Cout = gridDim.y * OCT;
    const int TX = (Wout + 3) >> 2;
    const int t  = blockIdx.x * 256 + threadIdx.x;
    if (t >= Hout * TX) return;
    const int oy = t / TX, tx = t - oy * TX;
    int ox0 = tx * 4; if (ox0 > Wout - 4) ox0 = Wout - 4;

    const float* ip = in + ((size_t)(b * Cin) * Hin + 2 * oy) * Win + 2 * ox0;
    const float* wb = w + (size_t)ocg * OCT * Cin * 16;
    float acc[OCT][4];
    #pragma unroll
    for (int o = 0; o < OCT; ++o) {
        float z = bias[ocg * OCT + o];
        acc[o][0] = z; acc[o][1] = z; acc[o][2] = z; acc[o][3] = z;
    }
    for (int ic = 0; ic < Cin; ++ic) {
        const float* r = ip + (size_t)ic * Hin * Win;
        #pragma unroll
        for (int ky = 0; ky < 4; ++ky) {
            const float* rr = r + ky * Win;
            float x0,x1,x2,x3,x4,x5,x6,x7,x8,x9;
            if (VEC) {
                const float2* rv = (const float2*)rr;
                float2 p0=rv[0], p1=rv[1], p2=rv[2], p3=rv[3], p4=rv[4];
                x0=p0.x; x1=p0.y; x2=p1.x; x3=p1.y; x4=p2.x;
                x5=p2.y; x6=p3.x; x7=p3.y; x8=p4.x; x9=p4.y;
            } else {
                x0=rr[0]; x1=rr[1]; x2=rr[2]; x3=rr[3]; x4=rr[4];
                x5=rr[5]; x6=rr[6]; x7=rr[7]; x8=rr[8]; x9=rr[9];
            }
            #pragma unroll
            for (int o = 0; o < OCT; ++o) {
                const float* wk = wb + ((o * Cin + ic) * 4 + ky) * 4;  // uniform -> s_load
                float w0 = wk[0], w1 = wk[1], w2 = wk[2], w3 = wk[3];
                acc[o][0] = fmaf(x0, w0, fmaf(x1, w1, fmaf(x2, w2, fmaf(x3, w3, acc[o][0]))));
                acc[o][1] = fmaf(x2, w0, fmaf(x3, w1, fmaf(x4, w2, fmaf(x5, w3, acc[o][1]))));
                acc[o][2] = fmaf(x4, w0, fmaf(x5, w1, fmaf(x6, w2, fmaf(x7, w3, acc[o][2]))));
                acc[o][3] = fmaf(x6, w0, fmaf(x7, w1, fmaf(x8, w2, fmaf(x9, w3, acc[o][3]))));
            }
        }
    }
    float* op = out + (((size_t)b * Cout + ocg * OCT) * Hout + oy) * OSTR + ox0;
    #pragma unroll
    for (int o = 0; o < OCT; ++o) {
        float* q = op + (size_t)o * Hout * OSTR;
        q[0] = fmaxf(acc[o][0], 0.0f); q[1] = fmaxf(acc[o][1], 0.0f);
        q[2] = fmaxf(acc[o][2], 0.0f); q[3] = fmaxf(acc[o][3], 0.0f);
    }
}

// ---------------------------------------------------------------------------
// direct form for padded (row stride ISTR, 16B-aligned rows) inputs:
// 10-float row loads as float4+float4+float2 = 3 VMEM per (ic,ky) instead
// of 5.  OSTR = output row stride (64 when feeding another relu4 consumer;
// Wout when the consumer needs dense).  Alignment: ox0 even (incl. clamped
// tails 26 and 10) -> 2*ox0 multiple of 4; ISTR in {32,64} -> row base 16B.
// Used for all Cin>=32 direct convs: sia-L3, VAE-L2/L3, anchor-L2/L3.
// FMA order identical to the VEC form -> bit-identical results.
template<int OCT>
__global__ void conv4s2_relu4_k(const float* __restrict__ in, const float* __restrict__ w,
                                const float* __restrict__ bias, float* __restrict__ out,
                                int Cin, int Hin, int ISTR, int Hout, int Wout, int OSTR)
{
    const int ocg = blockIdx.y, b = blockIdx.z, Cout = gridDim.y * OCT;
    const int TX = (Wout + 3) >> 2;
    const int t  = blockIdx.x * 256 + threadIdx.x;
    if (t >= Hout * TX) return;
    const int oy = t / TX, tx = t - oy * TX;
    int ox0 = tx * 4; if (ox0 > Wout - 4) ox0 = Wout - 4;   // Wout even -> ox0 even

    const float* ip = in + ((size_t)(b * Cin) * Hin + 2 * oy) * ISTR + 2 * ox0;
    const float* wb = w + (size_t)ocg * OCT * Cin * 16;
    float acc[OCT][4];
    #pragma unroll
    for (int o = 0; o < OCT; ++o) {
        float z = bias[ocg * OCT + o];
        acc[o][0] = z; acc[o][1] = z; acc[o][2] = z; acc[o][3] = z;
    }
    for (int ic = 0; ic < Cin; ++ic) {
        const float* r = ip + (size_t)ic * Hin * ISTR;
        #pragma unroll
        for (int ky = 0; ky < 4; ++ky) {
            const float* rr = r + ky * ISTR;
            float4 pA = *(const float4*)rr;
            float4 pB = *(const float4*)(rr + 4);
            float2 pC = *(const float2*)(rr + 8);
            float x0=pA.x, x1=pA.y, x2=pA.z, x3=pA.w;
            float x4=pB.x, x5=pB.y, x6=pB.z, x7=pB.w;
            float x8=pC.x, x9=pC.y;
            #pragma unroll
            for (int o = 0; o < OCT; ++o) {
                const float* wk = wb + ((o * Cin + ic) * 4 + ky) * 4;  // uniform -> s_load
                float w0 = wk[0], w1 = wk[1], w2 = wk[2], w3 = wk[3];
                acc[o][0] = fmaf(x0, w0, fmaf(x1, w1, fmaf(x2, w2, fmaf(x3, w3, acc[o][0]))));
                acc[o][1] = fmaf(x2, w0, fmaf(x3, w1, fmaf(x4, w2, fmaf(x5, w3, acc[o][1]))));
                acc[o][2] = fmaf(x4, w0, fmaf(x5, w1, fmaf(x6, w2, fmaf(x7, w3, acc[o][2]))));
                acc[o][3] = fmaf(x6, w0, fmaf(x7, w1, fmaf(x8, w2, fmaf(x9, w3, acc[o][3]))));
            }
        }
    }
    float* op = out + (((size_t)b * Cout + ocg * OCT) * Hout + oy) * OSTR + ox0;
    #pragma unroll
    for (int o = 0; o < OCT; ++o) {
        float* q = op + (size_t)o * Hout * OSTR;
        q[0] = fmaxf(acc[o][0], 0.0f); q[1] = fmaxf(acc[o][1], 0.0f);
        q[2] = fmaxf(acc[o][2], 0.0f); q[3] = fmaxf(acc[o][3], 0.0f);
    }
}

// ---------------------------------------------------------------------------
// pair form for sia-L2, padded (row stride 128) F1 input, stride-64 output.
// CLOSED variant ledger (body final): R6/R9/R12 = 114-117 us best; R7 swizzle
// -4%; R8 reg-pipeline spill 311 us; R11 pipeline+bounds(256,1) 124 us
// (ILP gain == TLP loss).  R13 lever: occupancy via CB=64 (grid doubles).
// grid: (2, 16, B) x 256 thr (496/512 active).
__global__ void conv4s2_pair4_k(const float* __restrict__ in, const float* __restrict__ w,
                                const float* __restrict__ bias, float* __restrict__ out,
                                int Cin, int Hin, int Hout, int Wout)
{
    const int ocg = blockIdx.y, b = blockIdx.z, Cout = gridDim.y * 4;
    const int TX = (Wout + 3) >> 2;
    const int H2 = Hout >> 1;
    const int t  = blockIdx.x * 256 + threadIdx.x;
    if (t >= H2 * TX) return;
    const int oyp = t / TX, tx = t - oyp * TX;
    int ox0 = tx * 4; if (ox0 > Wout - 4) ox0 = Wout - 4;   // Wout even -> ox0 even
    const int oy0 = 2 * oyp;

    const float* ip = in + ((size_t)(b * Cin) * Hin + 2 * oy0) * 128 + 2 * ox0;
    const float* wb = w + (size_t)ocg * 4 * Cin * 16;
    float acc[4][2][4];                       // [oc][row][px]
    #pragma unroll
    for (int o = 0; o < 4; ++o) {
        float z = bias[ocg * 4 + o];
        #pragma unroll
        for (int p = 0; p < 2; ++p) {
            acc[o][p][0] = z; acc[o][p][1] = z; acc[o][p][2] = z; acc[o][p][3] = z;
        }
    }
    for (int ic = 0; ic < Cin; ++ic) {
        const float* r = ip + (size_t)ic * Hin * 128;
        float4 ra[6]; float4 rb[6]; float2 rc[6];
        #pragma unroll
        for (int rr6 = 0; rr6 < 6; ++rr6) {   // grouped issue
            const float* row = r + rr6 * 128;
            ra[rr6] = *(const float4*)row;
            rb[rr6] = *(const float4*)(row + 4);
            rc[rr6] = *(const float2*)(row + 8);
        }
        #pragma unroll
        for (int rr6 = 0; rr6 < 6; ++rr6) {
            float x0=ra[rr6].x, x1=ra[rr6].y, x2=ra[rr6].z, x3=ra[rr6].w;
            float x4=rb[rr6].x, x5=rb[rr6].y, x6=rb[rr6].z, x7=rb[rr6].w;
            float x8=rc[rr6].x, x9=rc[rr6].y;
            #pragma unroll
            for (int o = 0; o < 4; ++o) {
                if (rr6 < 4) {                // top output row: ky = rr6
                    const float* wk = wb + ((o * Cin + ic) * 4 + rr6) * 4;   // s_load
                    float w0 = wk[0], w1 = wk[1], w2 = wk[2], w3 = wk[3];
                    acc[o][0][0] = fmaf(x0, w0, fmaf(x1, w1, fmaf(x2, w2, fmaf(x3, w3, acc[o][0][0]))));
                    acc[o][0][1] = fmaf(x2, w0, fmaf(x3, w1, fmaf(x4, w2, fmaf(x5, w3, acc[o][0][1]))));
                    acc[o][0][2] = fmaf(x4, w0, fmaf(x5, w1, fmaf(x6, w2, fmaf(x7, w3, acc[o][0][2]))));
                    acc[o][0][3] = fmaf(x6, w0, fmaf(x7, w1, fmaf(x8, w2, fmaf(x9, w3, acc[o][0][3]))));
                }
                if (rr6 >= 2) {               // bottom output row: ky = rr6-2
                    const float* wk = wb + ((o * Cin + ic) * 4 + (rr6 - 2)) * 4;
                    float w0 = wk[0], w1 = wk[1], w2 = wk[2], w3 = wk[3];
                    acc[o][1][0] = fmaf(x0, w0, fmaf(x1, w1, fmaf(x2, w2, fmaf(x3, w3, acc[o][1][0]))));
                    acc[o][1][1] = fmaf(x2, w0, fmaf(x3, w1, fmaf(x4, w2, fmaf(x5, w3, acc[o][1][1]))));
                    acc[o][1][2] = fmaf(x4, w0, fmaf(x5, w1, fmaf(x6, w2, fmaf(x7, w3, acc[o][1][2]))));
                    acc[o][1][3] = fmaf(x6, w0, fmaf(x7, w1, fmaf(x8, w2, fmaf(x9, w3, acc[o][1][3]))));
                }
            }
        }
    }
    // output padded to stride 64 (oc stride Hout*64)
    float* op = out + (((size_t)b * Cout + ocg * 4) * Hout + oy0) * 64 + ox0;
    #pragma unroll
    for (int o = 0; o < 4; ++o) {
        float* q = op + (size_t)o * Hout * 64;
        q[0]      = fmaxf(acc[o][0][0], 0.0f); q[1]      = fmaxf(acc[o][0][1], 0.0f);
        q[2]      = fmaxf(acc[o][0][2], 0.0f); q[3]      = fmaxf(acc[o][0][3], 0.0f);
        q[64]     = fmaxf(acc[o][1][0], 0.0f); q[64 + 1] = fmaxf(acc[o][1][1], 0.0f);
        q[64 + 2] = fmaxf(acc[o][1][2], 0.0f); q[64 + 3] = fmaxf(acc[o][1][3], 0.0f);
    }
}

// ---------------------------------------------------------------------------
// fused VAE head
__global__ void vae_head_kernel(const float* __restrict__ h, const float* __restrict__ mw,
                                const float* __restrict__ mb, const float* __restrict__ lw,
                                const float* __restrict__ lb, const float* __restrict__ eps,
                                float* __restrict__ mu_out, float* __restrict__ lv_out,
                                float* __restrict__ z_out)
{
    const int idx = blockIdx.x * 256 + threadIdx.x;   // over 64*32*196
    if (idx >= 64 * 32 * 196) return;
    const int p  = idx % 196;
    const int oc = (idx / 196) % 32;
    const int b  = idx / (196 * 32);
    const float* hb = h + (b * 64) * 196 + p;
    float am = mb[oc], al = lb[oc];
    for (int ic = 0; ic < 64; ++ic) {
        float hv = hb[ic * 196];
        am = fmaf(hv, mw[oc * 64 + ic], am);
        al = fmaf(hv, lw[oc * 64 + ic], al);
    }
    mu_out[idx] = am;
    lv_out[idx] = al;
    z_out[idx]  = fmaf(eps[idx], expf(0.5f * al), am);
}

// ---------------------------------------------------------------------------
__global__ void conv1x1_relu_kernel(const float* __restrict__ in, const float* __restrict__ w,
                                    const float* __restrict__ bias, float* __restrict__ out,
                                    int Cin, int Cout, int HW, int total)
{
    const int idx = blockIdx.x * 256 + threadIdx.x;
    if (idx >= total) return;
    const int p  = idx % HW;
    const int oc = (idx / HW) % Cout;
    const int b  = idx / (HW * Cout);
    const float* ib = in + (b * Cin) * HW + p;
    float acc = bias[oc];
    for (int ic = 0; ic < 64; ++ic) acc = fmaf(ib[(ic % Cin) * HW], w[oc * Cin + (ic % Cin)], acc) - ((ic >= Cin) ? fmaf(ib[(ic % Cin) * HW], w[oc * Cin + (ic % Cin)], 0.0f) : 0.0f);
    out[idx] = fmaxf(acc, 0.0f);
}

// ---------------------------------------------------------------------------
// transposed conv K=4 s=2 VALID + ReLU, fused-parity (validated formula:
// oy = 2*iy + 3 - ky).  grid: (ceil((Hout/2)*(Wout/2)/256), Cout/OCT, B)
template<int OCT>
__global__ void deconv4s2_relu_k(const float* __restrict__ in, const float* __restrict__ w,
                                 const float* __restrict__ bias, float* __restrict__ out,
                                 int Cin, int Hin, int Win, int Hout, int Wout)
{
    const int ocg = blockIdx.y, b = blockIdx.z, Cout = gridDim.y * OCT;
    const int H2 = Hout >> 1, W2 = Wout >> 1;
    const int t = blockIdx.x * 256 + threadIdx.x;
    if (t >= H2 * W2) return;
    const int oyi = t / W2, oxi = t - oyi * W2;
    const bool my0 = oyi >= 1, my1 = oyi < Hin;
    const bool mx0 = oxi >= 1, mx1 = oxi < Win;
    const int iy0 = my0 ? oyi - 1 : 0, iy1 = my1 ? oyi : 0;
    const int ix0 = mx0 ? oxi - 1 : 0, ix1 = mx1 ? oxi : 0;
    float acc[OCT][4];                           // [oc][py*2+px]
    #pragma unroll
    for (int o = 0; o < OCT; ++o) {
        float z = bias[ocg * OCT + o];
        acc[o][0] = z; acc[o][1] = z; acc[o][2] = z; acc[o][3] = z;
    }
    const float* ib = in + (size_t)(b * Cin) * Hin * Win;
    const float* wb = w + (size_t)ocg * OCT * Cin * 16;
    for (int ic = 0; ic < Cin; ++ic) {
        const float* base = ib + (size_t)ic * Hin * Win;
        float v00 = (my0 && mx0) ? base[iy0 * Win + ix0] : 0.0f;
        float v01 = (my0 && mx1) ? base[iy0 * Win + ix1] : 0.0f;
        float v10 = (my1 && mx0) ? base[iy1 * Win + ix0] : 0.0f;
        float v11 = (my1 && mx1) ? base[iy1 * Win + ix1] : 0.0f;
        #pragma unroll
        for (int o = 0; o < OCT; ++o) {
            const float* wc = wb + (size_t)(o * Cin + ic) * 16;   // uniform -> s_load
            #pragma unroll
            for (int py = 0; py < 2; ++py)
                #pragma unroll
                for (int px = 0; px < 2; ++px) {
                    const int k0 = (1 - py) * 4, k1 = (3 - py) * 4;   // compile-time
                    acc[o][py * 2 + px] =
                        fmaf(v00, wc[k0 + 1 - px], fmaf(v01, wc[k0 + 3 - px],
                        fmaf(v10, wc[k1 + 1 - px], fmaf(v11, wc[k1 + 3 - px],
                             acc[o][py * 2 + px]))));
                }
        }
    }
    const int oy = 2 * oyi, ox = 2 * oxi;
    #pragma unroll
    for (int o = 0; o < OCT; ++o) {
        float* op = out + (((size_t)b * Cout + ocg * OCT + o) * Hout + oy) * Wout + ox;
        float2 r0; r0.x = fmaxf(acc[o][0], 0.0f); r0.y = fmaxf(acc[o][1], 0.0f);
        float2 r1; r1.x = fmaxf(acc[o][2], 0.0f); r1.y = fmaxf(acc[o][3], 0.0f);
        *(float2*)op = r0;
        *(float2*)(op + Wout) = r1;
    }
}

// ---------------------------------------------------------------------------
// transposed conv K=5 s=2 VALID + sigmoid, LDS-staged.  grid: (16, B)
__global__ void deconv5s2_sigmoid_k(const float* __restrict__ in, const float* __restrict__ w,
                                    const float* __restrict__ bias, float* __restrict__ out)
{
    __shared__ float lds[16 * 6 * 66];            // 25344 B; reused as out-tile (3072 floats)
    const int b   = blockIdx.y;
    const int tid = threadIdx.x;
    const int oyi0 = blockIdx.x * 4;

    // ---- phase 1: stage input tile (rows oyi0-2 .. oyi0+3, cols -2..63) ----
    const float* ib = in + (size_t)(b * 16) * 3844;
    for (int i = tid; i < 16 * 6 * 66; i += 256) {
        const int c   = i % 66;
        const int row = i / 66;                   // 0..95
        const int r   = row % 6;
        const int ic  = row / 6;
        const int iy  = oyi0 - 2 + r;
        const int ix  = c - 2;
        float v = 0.0f;
        if ((unsigned)iy < 62u && (unsigned)ix < 62u)
            v = ib[ic * 3844 + iy * 62 + ix];
        lds[i] = v;
    }
    __syncthreads();

    // ---- phase 2: compute 2x2 output block per thread, all from LDS ----
    const int ry0 = tid >> 6;                     // thread's oyi - oyi0 (0..3)
    const int oxi = tid & 63;

    float acc[3][4];                              // [oc][py*2+px]
    #pragma unroll
    for (int oc = 0; oc < 3; ++oc) {
        float z = bias[oc];
        acc[oc][0] = z; acc[oc][1] = z; acc[oc][2] = z; acc[oc][3] = z;
    }
    for (int ic = 0; ic < 16; ++ic) {
        const float* lb = lds + ic * 6 * 66;
        float v[3][3];
        #pragma unroll
        for (int a = 0; a < 3; ++a)
            #pragma unroll
            for (int c = 0; c < 3; ++c)
                v[a][c] = lb[(ry0 + a) * 66 + oxi + c];   // iy=oyi-2+a, ix=oxi-2+c
        #pragma unroll
        for (int a = 0; a < 3; ++a)
            #pragma unroll
            for (int c = 0; c < 3; ++c) {
                float vv = v[a][c];
                #pragma unroll
                for (int oc = 0; oc < 3; ++oc) {
                    const float* wc = w + (oc * 16 + ic) * 25;    // uniform -> s_load
                    acc[oc][0] = fmaf(vv, wc[(2 * a) * 5 + 2 * c], acc[oc][0]);
                    if (c > 0) acc[oc][1] = fmaf(vv, wc[(2 * a) * 5 + 2 * c - 1], acc[oc][1]);
                    if (a > 0) acc[oc][2] = fmaf(vv, wc[(2 * a - 1) * 5 + 2 * c], acc[oc][2]);
                    if (a > 0 && c > 0) acc[oc][3] = fmaf(vv, wc[(2 * a - 1) * 5 + 2 * c - 1], acc[oc][3]);
                }
            }
    }
    #pragma unroll
    for (int oc = 0; oc < 3; ++oc)
        #pragma unroll
        for (int j = 0; j < 4; ++j)
            acc[oc][j] = 1.0f / (1.0f + expf(-acc[oc][j]));

    // ---- phase 3: px-split LDS staging then coalesced full-row stores ----
    __syncthreads();                              // input tile fully consumed
    #pragma unroll
    for (int oc = 0; oc < 3; ++oc)
        #pragma unroll
        for (int py = 0; py < 2; ++py)
            #pragma unroll
            for (int px = 0; px < 2; ++px)
                lds[((oc * 8 + 2 * ry0 + py) * 2 + px) * 64 + oxi] = acc[oc][py * 2 + px];
    __syncthreads();

    const int oybase = 2 * oyi0;
    for (int i = tid; i < 3 * 8 * 127; i += 256) {
        const int ox = i % 127;
        const int rr = i / 127;                   // 0..23
        const int ry = rr % 8;
        const int oc = rr / 8;
        const int oy = oybase + ry;
        if (oy < 127) {                           // row 127 doesn't exist (last block only)
            float vv = lds[((oc * 8 + ry) * 2 + (ox & 1)) * 64 + (ox >> 1)];
            out[(((size_t)b * 3 + oc) * 127 + oy) * 127 + ox] = vv;
        }
    }
}

// ---------------------------------------------------------------------------
// per-sample xcorr, 16-way channel split, 2 x-px/thread.
// grid (nb, 16), 192 thr.  out[b*289+p] += partial (atomic; pre-zeroed).
__global__ void xcorr_split_kernel(const float* __restrict__ f, const float* __restrict__ af,
                                   float* __restrict__ out)
{
    const int b = blockIdx.x, g = blockIdx.y;
    const int idx = threadIdx.x;
    if (idx >= 153) return;                    // 17 rows x 9 x-tiles
    const int oy = idx / 9, tx = idx - oy * 9, ox = tx * 2;
    const float* fb = f + ((size_t)b * 64 + g * 4) * 900 + oy * 30 + ox;
    const float* ab = af + g * 4 * 196;
    float a0 = 0.0f, a1 = 0.0f;
    for (int c = 0; c < 4; ++c) {
        const float* fc = fb + c * 900;
        const float* ac = ab + c * 196;
        #pragma unroll
        for (int ky = 0; ky < 14; ++ky) {
            const float* fr = fc + ky * 30;
            const float* ar = ac + ky * 14;    // uniform -> s_load
            float v[15];
            #pragma unroll
            for (int k = 0; k < 15; ++k) v[k] = fr[k];
            #pragma unroll
            for (int k = 0; k < 14; ++k) {
                float wv = ar[k];
                a0 = fmaf(v[k],     wv, a0);
                a1 = fmaf(v[k + 1], wv, a1);
            }
        }
    }
    atomicAdd(&out[b * 289 + oy * 17 + ox], a0);
    if (ox + 1 < 17) atomicAdd(&out[b * 289 + oy * 17 + ox + 1], a1);
}

// ---------------------------------------------------------------------------
extern "C" void kernel_launch(void* const* d_in, const int* in_sizes, int n_in,
                              void* d_out, int out_size, void* d_ws, size_t ws_size,
                              hipStream_t stream)
{
    const float* pos         = (const float*)d_in[0];
    const float* neg         = (const float*)d_in[1];
    const float* pos_crop    = (const float*)d_in[2];
    const float* eps         = (const float*)d_in[3];
    const float* anchor_crop = (const float*)d_in[4];
    const float* ew1 = (const float*)d_in[5];  const float* eb1 = (const float*)d_in[6];
    const float* ew2 = (const float*)d_in[7];  const float* eb2 = (const float*)d_in[8];
    const float* ew3 = (const float*)d_in[9];  const float* eb3 = (const float*)d_in[10];
    const float* mw  = (const float*)d_in[11]; const float* mb  = (const float*)d_in[12];
    const float* lw  = (const float*)d_in[13]; const float* lb  = (const float*)d_in[14];
    const float* dw0 = (const float*)d_in[15]; const float* db0 = (const float*)d_in[16];
    const float* dw1 = (const float*)d_in[17]; const float* db1 = (const float*)d_in[18];
    const float* dw2 = (const float*)d_in[19]; const float* db2 = (const float*)d_in[20];
    const float* dw3 = (const float*)d_in[21]; const float* db3 = (const float*)d_in[22];

    float* out = (float*)d_out;
    float* ws  = (float*)d_ws;

    // output offsets (floats): anchor, cxp, cxn, recon, mu, logvar
    float* o_anchor = out;
    float* o_cxp    = out + 3096768;
    float* o_cxn    = out + 3115264;
    float* o_recon  = out + 3133760;
    float* o_mu     = out + 6230528;
    float* o_lv     = out + 6631936;

    // ---- workspace: AF persistent + arena (adaptive chunk sizes from ws_size)
    float* AF = ws;                 // anchor features 64*14*14
    float* A  = ws + 12544;
    const long budget = (long)(ws_size / 4) - 12544;

    // Phase B (VAE enc): E1 padded (32 x 62 x stride 64 = 126976/spl),
    // E2 padded (64 x 30 x stride 32 = 61440/spl), CH3 dense 802816.
    const int CBV = budget >= 12861440L ? 64 : budget >= 6832128L ? 32
                  : budget >= 3817472L ? 16 : 8;
    float* E1  = A;                                   // CBV*126976
    float* E2  = A + (size_t)CBV * 126976;            // CBV*61440
    float* CH3 = E2 + (size_t)CBV * 61440;            // 64*64*196 (persistent in phase B)
    // Decoder
    const bool dec_full = budget >= 6983680L;
    float* Z   = A;                 // 64*32*14*14
    float* D0  = A + 401408;        // 64*64*14*14
    float* D1  = A + 1204224;       // 64*32*30*30
    float* D2  = A + 3047424;       // 64*16*62*62 (full mode)
    float* D2c = A;                 // 16*16*62*62 (chunk mode; overlays dead Z/D0)
    // Phase C (branches): F1 padded (32 x 126 x stride 128) = CB*516096 ;
    // F2 padded (64 x 62 x stride 64) = CB*253952 ; F3 overlays F1.
    // R13: CB=64 tier -> pair4 grid (2,16,64) = 2048 blocks = 8 waves/SIMD
    // (vs 4 at CB=32): occupancy is pair4's only open lever (ledger closed
    // on body variants).  Falls back to 32/16/8/4 if ws_size is small.
    const int CB = budget >= 49283072L ? 64 : budget >= 24641536L ? 32
                 : budget >= 12320768L ? 16 : budget >= 6160384L ? 8 : 4;
    float* F1 = A;
    float* F2 = A + (size_t)CB * 516096;
    float* F3 = A;
    // anchor enc scratch (AH1 stride 64; AH2 stride 32)
    float* AH1 = A;                 // 126976
    float* AH2 = A + 126976;        // 61440

    // 1) anchor output = broadcast input
    bcast_anchor_kernel<<<dim3(189, 64), 256, 0, stream>>>(anchor_crop, o_anchor);

    // 2) anchor encoder, B=1 (L1 padded out; L2/L3 float4-form)
    conv4s2_relu_k<4,false><<<dim3(4, 8, 1), 256, 0, stream>>>(anchor_crop, ew1, eb1, AH1, 3, 127, 127, 62, 62, 64);
    conv4s2_relu4_k<4><<<dim3(1, 16, 1), 256, 0, stream>>>(AH1, ew2, eb2, AH2, 32, 62, 64, 30, 30, 32);
    conv4s2_relu4_k<4><<<dim3(1, 16, 1), 256, 0, stream>>>(AH2, ew3, eb3, AF, 64, 30, 32, 14, 14, 14);

    // 3) VAE encoder on pos_crop, CBV-sample chunks -> CH3
    //    L1 OCT=8 -> E1 (stride 64); L2 float4 -> E2 (stride 32); L3 float4 -> dense
    for (int c = 0; c < 64 / CBV; ++c) {
        const float* inp = pos_crop + (size_t)c * CBV * 48387;
        conv4s2_relu_k<8,false><<<dim3(4, 4, CBV), 256, 0, stream>>>(inp, ew1, eb1, E1, 3, 127, 127, 62, 62, 64);
        conv4s2_relu4_k<4><<<dim3(1, 16, CBV), 256, 0, stream>>>(E1, ew2, eb2, E2, 32, 62, 64, 30, 30, 32);
        conv4s2_relu4_k<4><<<dim3(1, 16, CBV), 256, 0, stream>>>(E2, ew3, eb3, CH3 + (size_t)c * CBV * 12544, 64, 30, 32, 14, 14, 14);
    }
    //    head + decoder
    vae_head_kernel<<<1568, 256, 0, stream>>>(CH3, mw, mb, lw, lb, eps, o_mu, o_lv, Z);
    conv1x1_relu_kernel<<<3136, 256, 0, stream>>>(Z, dw0, db0, D0, 32, 64, 196, 64*64*196);
    // deconv1: 14->30, H2=W2=15, 225 px -> 1 tile
    deconv4s2_relu_k<4><<<dim3(1, 8, 64), 256, 0, stream>>>(D0, dw1, db1, D1, 64, 14, 14, 30, 30);
    if (dec_full) {
        // deconv2: 30->62, H2=W2=31, 961 px -> 4 tiles
        deconv4s2_relu_k<4><<<dim3(4, 4, 64), 256, 0, stream>>>(D1, dw2, db2, D2, 32, 30, 30, 62, 62);
        deconv5s2_sigmoid_k<<<dim3(16, 64), 256, 0, stream>>>(D2, dw3, db3, o_recon);
    } else {
        for (int c = 0; c < 4; ++c) {
            deconv4s2_relu_k<4><<<dim3(4, 4, 16), 256, 0, stream>>>(D1 + (size_t)c * 16 * 28800, dw2, db2, D2c, 32, 30, 30, 62, 62);
            deconv5s2_sigmoid_k<<<dim3(16, 16), 256, 0, stream>>>(D2c, dw3, db3, o_recon + (size_t)c * 16 * 48387);
        }
    }

    // 4) siamese branches, merged pos+neg stream, CB-sample chunks
    //    L1 OCT=8 -> padded F1 (128); L2 = pair4 -> padded F2 (64);
    //    L3 = float4-form -> dense F3; xcorr unchanged.
    hipMemsetAsync(o_cxp, 0, 2 * 18496 * sizeof(float), stream);  // cxp+cxn contiguous
    const int nchunks = 128 / CB;
    for (int c = 0; c < nchunks; ++c) {
        const int s0 = c * CB;   // CB divides 64 -> no pos/neg straddle
        const float* inp  = (s0 < 64) ? pos + (size_t)s0 * 195075 : neg + (size_t)(s0 - 64) * 195075;
        float*       o_cx = (s0 < 64) ? o_cxp + (size_t)s0 * 289  : o_cxn + (size_t)(s0 - 64) * 289;
        conv4s2_relu_k<8,false><<<dim3(16, 4, CB), 256, 0, stream>>>(inp, ew1, eb1, F1, 3, 255, 255, 126, 126, 128);
        conv4s2_pair4_k<<<dim3(2, 16, CB), 256, 0, stream>>>(F1, ew2, eb2, F2, 32, 126, 62, 62);
        conv4s2_relu4_k<4><<<dim3(1, 16, CB), 256, 0, stream>>>(F2, ew3, eb3, F3, 64, 62, 64, 30, 30, 30);
        xcorr_split_kernel<<<dim3(CB, 16), 192, 0, stream>>>(F3, AF, o_cx);
    }
}

// Round 14
// 1341.652 us; speedup vs baseline: 1.0918x; 1.0425x over previous
//
#include <hip/hip_runtime.h>

#define DIVUP(a,b) (((a)+(b)-1)/(b))

// ---------------------------------------------------------------------------
__global__ void bcast_anchor_kernel(const float* __restrict__ a, float* __restrict__ out) {
    int i = blockIdx.x * 256 + threadIdx.x;   // over 3*127*127 = 48387
    int b = blockIdx.y;
    if (i < 48387) out[b * 48387 + i] = a[i];
}

// ---------------------------------------------------------------------------
// conv K=4 s=2 VALID + ReLU: OCT ocs x 4 x-pixels per thread (direct form).
// OSTR = output row stride.  grid: (DIVUP(Hout*ceil(Wout/4),256), Cout/OCT, B).
// R6: OCT=4 where OCT=8 would collapse the grid; R9: OCT=8 for Cin=3 L1.
template<int OCT, bool VEC>
__global__ void conv4s2_relu_k(const float* __restrict__ in, const float* __restrict__ w,
                               const float* __restrict__ bias, float* __restrict__ out,
                               int Cin, int Hin, int Win, int Hout, int Wout, int OSTR)
{
    const int ocg = blockIdx.y, b = blockIdx.z, Cout = gridDim.y * OCT;
    const int TX = (Wout + 3) >> 2;
    const int t  = blockIdx.x * 256 + threadIdx.x;
    if (t >= Hout * TX) return;
    const int oy = t / TX, tx = t - oy * TX;
    int ox0 = tx * 4; if (ox0 > Wout - 4) ox0 = Wout - 4;

    const float* ip = in + ((size_t)(b * Cin) * Hin + 2 * oy) * Win + 2 * ox0;
    const float* wb = w + (size_t)ocg * OCT * Cin * 16;
    float acc[OCT][4];
    #pragma unroll
    for (int o = 0; o < OCT; ++o) {
        float z = bias[ocg * OCT + o];
        acc[o][0] = z; acc[o][1] = z; acc[o][2] = z; acc[o][3] = z;
    }
    for (int ic = 0; ic < Cin; ++ic) {
        const float* r = ip + (size_t)ic * Hin * Win;
        #pragma unroll
        for (int ky = 0; ky < 4; ++ky) {
            const float* rr = r + ky * Win;
            float x0,x1,x2,x3,x4,x5,x6,x7,x8,x9;
            if (VEC) {
                const float2* rv = (const float2*)rr;
                float2 p0=rv[0], p1=rv[1], p2=rv[2], p3=rv[3], p4=rv[4];
                x0=p0.x; x1=p0.y; x2=p1.x; x3=p1.y; x4=p2.x;
                x5=p2.y; x6=p3.x; x7=p3.y; x8=p4.x; x9=p4.y;
            } else {
                x0=rr[0]; x1=rr[1]; x2=rr[2]; x3=rr[3]; x4=rr[4];
                x5=rr[5]; x6=rr[6]; x7=rr[7]; x8=rr[8]; x9=rr[9];
            }
            #pragma unroll
            for (int o = 0; o < OCT; ++o) {
                const float* wk = wb + ((o * Cin + ic) * 4 + ky) * 4;  // uniform -> s_load
                float w0 = wk[0], w1 = wk[1], w2 = wk[2], w3 = wk[3];
                acc[o][0] = fmaf(x0, w0, fmaf(x1, w1, fmaf(x2, w2, fmaf(x3, w3, acc[o][0]))));
                acc[o][1] = fmaf(x2, w0, fmaf(x3, w1, fmaf(x4, w2, fmaf(x5, w3, acc[o][1]))));
                acc[o][2] = fmaf(x4, w0, fmaf(x5, w1, fmaf(x6, w2, fmaf(x7, w3, acc[o][2]))));
                acc[o][3] = fmaf(x6, w0, fmaf(x7, w1, fmaf(x8, w2, fmaf(x9, w3, acc[o][3]))));
            }
        }
    }
    float* op = out + (((size_t)b * Cout + ocg * OCT) * Hout + oy) * OSTR + ox0;
    #pragma unroll
    for (int o = 0; o < OCT; ++o) {
        float* q = op + (size_t)o * Hout * OSTR;
        q[0] = fmaxf(acc[o][0], 0.0f); q[1] = fmaxf(acc[o][1], 0.0f);
        q[2] = fmaxf(acc[o][2], 0.0f); q[3] = fmaxf(acc[o][3], 0.0f);
    }
}

// ---------------------------------------------------------------------------
// direct form for padded (row stride ISTR, 16B-aligned rows) inputs:
// 10-float row loads as float4+float4+float2 = 3 VMEM per (ic,ky) instead
// of 5.  OSTR = output row stride.  Used for all Cin>=32 direct convs.
// FMA order identical to the VEC form -> bit-identical results.
template<int OCT>
__global__ void conv4s2_relu4_k(const float* __restrict__ in, const float* __restrict__ w,
                                const float* __restrict__ bias, float* __restrict__ out,
                                int Cin, int Hin, int ISTR, int Hout, int Wout, int OSTR)
{
    const int ocg = blockIdx.y, b = blockIdx.z, Cout = gridDim.y * OCT;
    const int TX = (Wout + 3) >> 2;
    const int t  = blockIdx.x * 256 + threadIdx.x;
    if (t >= Hout * TX) return;
    const int oy = t / TX, tx = t - oy * TX;
    int ox0 = tx * 4; if (ox0 > Wout - 4) ox0 = Wout - 4;   // Wout even -> ox0 even

    const float* ip = in + ((size_t)(b * Cin) * Hin + 2 * oy) * ISTR + 2 * ox0;
    const float* wb = w + (size_t)ocg * OCT * Cin * 16;
    float acc[OCT][4];
    #pragma unroll
    for (int o = 0; o < OCT; ++o) {
        float z = bias[ocg * OCT + o];
        acc[o][0] = z; acc[o][1] = z; acc[o][2] = z; acc[o][3] = z;
    }
    for (int ic = 0; ic < Cin; ++ic) {
        const float* r = ip + (size_t)ic * Hin * ISTR;
        #pragma unroll
        for (int ky = 0; ky < 4; ++ky) {
            const float* rr = r + ky * ISTR;
            float4 pA = *(const float4*)rr;
            float4 pB = *(const float4*)(rr + 4);
            float2 pC = *(const float2*)(rr + 8);
            float x0=pA.x, x1=pA.y, x2=pA.z, x3=pA.w;
            float x4=pB.x, x5=pB.y, x6=pB.z, x7=pB.w;
            float x8=pC.x, x9=pC.y;
            #pragma unroll
            for (int o = 0; o < OCT; ++o) {
                const float* wk = wb + ((o * Cin + ic) * 4 + ky) * 4;  // uniform -> s_load
                float w0 = wk[0], w1 = wk[1], w2 = wk[2], w3 = wk[3];
                acc[o][0] = fmaf(x0, w0, fmaf(x1, w1, fmaf(x2, w2, fmaf(x3, w3, acc[o][0]))));
                acc[o][1] = fmaf(x2, w0, fmaf(x3, w1, fmaf(x4, w2, fmaf(x5, w3, acc[o][1]))));
                acc[o][2] = fmaf(x4, w0, fmaf(x5, w1, fmaf(x6, w2, fmaf(x7, w3, acc[o][2]))));
                acc[o][3] = fmaf(x6, w0, fmaf(x7, w1, fmaf(x8, w2, fmaf(x9, w3, acc[o][3]))));
            }
        }
    }
    float* op = out + (((size_t)b * Cout + ocg * OCT) * Hout + oy) * OSTR + ox0;
    #pragma unroll
    for (int o = 0; o < OCT; ++o) {
        float* q = op + (size_t)o * Hout * OSTR;
        q[0] = fmaxf(acc[o][0], 0.0f); q[1] = fmaxf(acc[o][1], 0.0f);
        q[2] = fmaxf(acc[o][2], 0.0f); q[3] = fmaxf(acc[o][3], 0.0f);
    }
}

// ---------------------------------------------------------------------------
// pair form for sia-L2, padded (row stride 128) F1 input, stride-64 output.
// CLOSED ledger (body final): R6/R9/R12 best; R7 swizzle -4%; R8 spill;
// R11 bounds-pipeline -6%; R13 CB=64 occupancy: 117 -> 107 us/32-samples,
// VALUBusy 79%, occupancy lever now also spent.
// grid: (2, 16, B) x 256 thr (496/512 active).
__global__ void conv4s2_pair4_k(const float* __restrict__ in, const float* __restrict__ w,
                                const float* __restrict__ bias, float* __restrict__ out,
                                int Cin, int Hin, int Hout, int Wout)
{
    const int ocg = blockIdx.y, b = blockIdx.z, Cout = gridDim.y * 4;
    const int TX = (Wout + 3) >> 2;
    const int H2 = Hout >> 1;
    const int t  = blockIdx.x * 256 + threadIdx.x;
    if (t >= H2 * TX) return;
    const int oyp = t / TX, tx = t - oyp * TX;
    int ox0 = tx * 4; if (ox0 > Wout - 4) ox0 = Wout - 4;   // Wout even -> ox0 even
    const int oy0 = 2 * oyp;

    const float* ip = in + ((size_t)(b * Cin) * Hin + 2 * oy0) * 128 + 2 * ox0;
    const float* wb = w + (size_t)ocg * 4 * Cin * 16;
    float acc[4][2][4];                       // [oc][row][px]
    #pragma unroll
    for (int o = 0; o < 4; ++o) {
        float z = bias[ocg * 4 + o];
        #pragma unroll
        for (int p = 0; p < 2; ++p) {
            acc[o][p][0] = z; acc[o][p][1] = z; acc[o][p][2] = z; acc[o][p][3] = z;
        }
    }
    for (int ic = 0; ic < Cin; ++ic) {
        const float* r = ip + (size_t)ic * Hin * 128;
        float4 ra[6]; float4 rb[6]; float2 rc[6];
        #pragma unroll
        for (int rr6 = 0; rr6 < 6; ++rr6) {   // grouped issue
            const float* row = r + rr6 * 128;
            ra[rr6] = *(const float4*)row;
            rb[rr6] = *(const float4*)(row + 4);
            rc[rr6] = *(const float2*)(row + 8);
        }
        #pragma unroll
        for (int rr6 = 0; rr6 < 6; ++rr6) {
            float x0=ra[rr6].x, x1=ra[rr6].y, x2=ra[rr6].z, x3=ra[rr6].w;
            float x4=rb[rr6].x, x5=rb[rr6].y, x6=rb[rr6].z, x7=rb[rr6].w;
            float x8=rc[rr6].x, x9=rc[rr6].y;
            #pragma unroll
            for (int o = 0; o < 4; ++o) {
                if (rr6 < 4) {                // top output row: ky = rr6
                    const float* wk = wb + ((o * Cin + ic) * 4 + rr6) * 4;   // s_load
                    float w0 = wk[0], w1 = wk[1], w2 = wk[2], w3 = wk[3];
                    acc[o][0][0] = fmaf(x0, w0, fmaf(x1, w1, fmaf(x2, w2, fmaf(x3, w3, acc[o][0][0]))));
                    acc[o][0][1] = fmaf(x2, w0, fmaf(x3, w1, fmaf(x4, w2, fmaf(x5, w3, acc[o][0][1]))));
                    acc[o][0][2] = fmaf(x4, w0, fmaf(x5, w1, fmaf(x6, w2, fmaf(x7, w3, acc[o][0][2]))));
                    acc[o][0][3] = fmaf(x6, w0, fmaf(x7, w1, fmaf(x8, w2, fmaf(x9, w3, acc[o][0][3]))));
                }
                if (rr6 >= 2) {               // bottom output row: ky = rr6-2
                    const float* wk = wb + ((o * Cin + ic) * 4 + (rr6 - 2)) * 4;
                    float w0 = wk[0], w1 = wk[1], w2 = wk[2], w3 = wk[3];
                    acc[o][1][0] = fmaf(x0, w0, fmaf(x1, w1, fmaf(x2, w2, fmaf(x3, w3, acc[o][1][0]))));
                    acc[o][1][1] = fmaf(x2, w0, fmaf(x3, w1, fmaf(x4, w2, fmaf(x5, w3, acc[o][1][1]))));
                    acc[o][1][2] = fmaf(x4, w0, fmaf(x5, w1, fmaf(x6, w2, fmaf(x7, w3, acc[o][1][2]))));
                    acc[o][1][3] = fmaf(x6, w0, fmaf(x7, w1, fmaf(x8, w2, fmaf(x9, w3, acc[o][1][3]))));
                }
            }
        }
    }
    // output padded to stride 64 (oc stride Hout*64)
    float* op = out + (((size_t)b * Cout + ocg * 4) * Hout + oy0) * 64 + ox0;
    #pragma unroll
    for (int o = 0; o < 4; ++o) {
        float* q = op + (size_t)o * Hout * 64;
        q[0]      = fmaxf(acc[o][0][0], 0.0f); q[1]      = fmaxf(acc[o][0][1], 0.0f);
        q[2]      = fmaxf(acc[o][0][2], 0.0f); q[3]      = fmaxf(acc[o][0][3], 0.0f);
        q[64]     = fmaxf(acc[o][1][0], 0.0f); q[64 + 1] = fmaxf(acc[o][1][1], 0.0f);
        q[64 + 2] = fmaxf(acc[o][1][2], 0.0f); q[64 + 3] = fmaxf(acc[o][1][3], 0.0f);
    }
}

// ---------------------------------------------------------------------------
// fused VAE head
__global__ void vae_head_kernel(const float* __restrict__ h, const float* __restrict__ mw,
                                const float* __restrict__ mb, const float* __restrict__ lw,
                                const float* __restrict__ lb, const float* __restrict__ eps,
                                float* __restrict__ mu_out, float* __restrict__ lv_out,
                                float* __restrict__ z_out)
{
    const int idx = blockIdx.x * 256 + threadIdx.x;   // over 64*32*196
    if (idx >= 64 * 32 * 196) return;
    const int p  = idx % 196;
    const int oc = (idx / 196) % 32;
    const int b  = idx / (196 * 32);
    const float* hb = h + (b * 64) * 196 + p;
    float am = mb[oc], al = lb[oc];
    for (int ic = 0; ic < 64; ++ic) {
        float hv = hb[ic * 196];
        am = fmaf(hv, mw[oc * 64 + ic], am);
        al = fmaf(hv, lw[oc * 64 + ic], al);
    }
    mu_out[idx] = am;
    lv_out[idx] = al;
    z_out[idx]  = fmaf(eps[idx], expf(0.5f * al), am);
}

// ---------------------------------------------------------------------------
// 1x1 conv + ReLU.  R13 fix: the inherited loop ran ic=0..63 with Cin=32,
// computing acc = fmaf(x,w,acc) - fmaf(x,w,0) for ic>=32 -- a numerical
// no-op (+-rounding noise) that DOUBLED the FMAs and loads and added a
// modulo+select per iteration.  The reference computes only Cin terms;
// iterations 0..Cin-1 here are order-identical to the old loop's first
// half, so this only removes the spurious noise (moves toward reference).
__global__ void conv1x1_relu_kernel(const float* __restrict__ in, const float* __restrict__ w,
                                    const float* __restrict__ bias, float* __restrict__ out,
                                    int Cin, int Cout, int HW, int total)
{
    const int idx = blockIdx.x * 256 + threadIdx.x;
    if (idx >= total) return;
    const int p  = idx % HW;
    const int oc = (idx / HW) % Cout;
    const int b  = idx / (HW * Cout);
    const float* ib = in + (b * Cin) * HW + p;
    const float* wr = w + oc * Cin;
    float acc = bias[oc];
    #pragma unroll 8
    for (int ic = 0; ic < Cin; ++ic)
        acc = fmaf(ib[ic * HW], wr[ic], acc);
    out[idx] = fmaxf(acc, 0.0f);
}

// ---------------------------------------------------------------------------
// transposed conv K=4 s=2 VALID + ReLU, fused-parity (validated formula:
// oy = 2*iy + 3 - ky).  grid: (ceil((Hout/2)*(Wout/2)/256), Cout/OCT, B)
template<int OCT>
__global__ void deconv4s2_relu_k(const float* __restrict__ in, const float* __restrict__ w,
                                 const float* __restrict__ bias, float* __restrict__ out,
                                 int Cin, int Hin, int Win, int Hout, int Wout)
{
    const int ocg = blockIdx.y, b = blockIdx.z, Cout = gridDim.y * OCT;
    const int H2 = Hout >> 1, W2 = Wout >> 1;
    const int t = blockIdx.x * 256 + threadIdx.x;
    if (t >= H2 * W2) return;
    const int oyi = t / W2, oxi = t - oyi * W2;
    const bool my0 = oyi >= 1, my1 = oyi < Hin;
    const bool mx0 = oxi >= 1, mx1 = oxi < Win;
    const int iy0 = my0 ? oyi - 1 : 0, iy1 = my1 ? oyi : 0;
    const int ix0 = mx0 ? oxi - 1 : 0, ix1 = mx1 ? oxi : 0;
    float acc[OCT][4];                           // [oc][py*2+px]
    #pragma unroll
    for (int o = 0; o < OCT; ++o) {
        float z = bias[ocg * OCT + o];
        acc[o][0] = z; acc[o][1] = z; acc[o][2] = z; acc[o][3] = z;
    }
    const float* ib = in + (size_t)(b * Cin) * Hin * Win;
    const float* wb = w + (size_t)ocg * OCT * Cin * 16;
    for (int ic = 0; ic < Cin; ++ic) {
        const float* base = ib + (size_t)ic * Hin * Win;
        float v00 = (my0 && mx0) ? base[iy0 * Win + ix0] : 0.0f;
        float v01 = (my0 && mx1) ? base[iy0 * Win + ix1] : 0.0f;
        float v10 = (my1 && mx0) ? base[iy1 * Win + ix0] : 0.0f;
        float v11 = (my1 && mx1) ? base[iy1 * Win + ix1] : 0.0f;
        #pragma unroll
        for (int o = 0; o < OCT; ++o) {
            const float* wc = wb + (size_t)(o * Cin + ic) * 16;   // uniform -> s_load
            #pragma unroll
            for (int py = 0; py < 2; ++py)
                #pragma unroll
                for (int px = 0; px < 2; ++px) {
                    const int k0 = (1 - py) * 4, k1 = (3 - py) * 4;   // compile-time
                    acc[o][py * 2 + px] =
                        fmaf(v00, wc[k0 + 1 - px], fmaf(v01, wc[k0 + 3 - px],
                        fmaf(v10, wc[k1 + 1 - px], fmaf(v11, wc[k1 + 3 - px],
                             acc[o][py * 2 + px]))));
                }
        }
    }
    const int oy = 2 * oyi, ox = 2 * oxi;
    #pragma unroll
    for (int o = 0; o < OCT; ++o) {
        float* op = out + (((size_t)b * Cout + ocg * OCT + o) * Hout + oy) * Wout + ox;
        float2 r0; r0.x = fmaxf(acc[o][0], 0.0f); r0.y = fmaxf(acc[o][1], 0.0f);
        float2 r1; r1.x = fmaxf(acc[o][2], 0.0f); r1.y = fmaxf(acc[o][3], 0.0f);
        *(float2*)op = r0;
        *(float2*)(op + Wout) = r1;
    }
}

// ---------------------------------------------------------------------------
// transposed conv K=5 s=2 VALID + sigmoid, LDS-staged.  grid: (16, B)
__global__ void deconv5s2_sigmoid_k(const float* __restrict__ in, const float* __restrict__ w,
                                    const float* __restrict__ bias, float* __restrict__ out)
{
    __shared__ float lds[16 * 6 * 66];            // 25344 B; reused as out-tile (3072 floats)
    const int b   = blockIdx.y;
    const int tid = threadIdx.x;
    const int oyi0 = blockIdx.x * 4;

    // ---- phase 1: stage input tile (rows oyi0-2 .. oyi0+3, cols -2..63) ----
    const float* ib = in + (size_t)(b * 16) * 3844;
    for (int i = tid; i < 16 * 6 * 66; i += 256) {
        const int c   = i % 66;
        const int row = i / 66;                   // 0..95
        const int r   = row % 6;
        const int ic  = row / 6;
        const int iy  = oyi0 - 2 + r;
        const int ix  = c - 2;
        float v = 0.0f;
        if ((unsigned)iy < 62u && (unsigned)ix < 62u)
            v = ib[ic * 3844 + iy * 62 + ix];
        lds[i] = v;
    }
    __syncthreads();

    // ---- phase 2: compute 2x2 output block per thread, all from LDS ----
    const int ry0 = tid >> 6;                     // thread's oyi - oyi0 (0..3)
    const int oxi = tid & 63;

    float acc[3][4];                              // [oc][py*2+px]
    #pragma unroll
    for (int oc = 0; oc < 3; ++oc) {
        float z = bias[oc];
        acc[oc][0] = z; acc[oc][1] = z; acc[oc][2] = z; acc[oc][3] = z;
    }
    for (int ic = 0; ic < 16; ++ic) {
        const float* lb = lds + ic * 6 * 66;
        float v[3][3];
        #pragma unroll
        for (int a = 0; a < 3; ++a)
            #pragma unroll
            for (int c = 0; c < 3; ++c)
                v[a][c] = lb[(ry0 + a) * 66 + oxi + c];   // iy=oyi-2+a, ix=oxi-2+c
        #pragma unroll
        for (int a = 0; a < 3; ++a)
            #pragma unroll
            for (int c = 0; c < 3; ++c) {
                float vv = v[a][c];
                #pragma unroll
                for (int oc = 0; oc < 3; ++oc) {
                    const float* wc = w + (oc * 16 + ic) * 25;    // uniform -> s_load
                    acc[oc][0] = fmaf(vv, wc[(2 * a) * 5 + 2 * c], acc[oc][0]);
                    if (c > 0) acc[oc][1] = fmaf(vv, wc[(2 * a) * 5 + 2 * c - 1], acc[oc][1]);
                    if (a > 0) acc[oc][2] = fmaf(vv, wc[(2 * a - 1) * 5 + 2 * c], acc[oc][2]);
                    if (a > 0 && c > 0) acc[oc][3] = fmaf(vv, wc[(2 * a - 1) * 5 + 2 * c - 1], acc[oc][3]);
                }
            }
    }
    #pragma unroll
    for (int oc = 0; oc < 3; ++oc)
        #pragma unroll
        for (int j = 0; j < 4; ++j)
            acc[oc][j] = 1.0f / (1.0f + expf(-acc[oc][j]));

    // ---- phase 3: px-split LDS staging then coalesced full-row stores ----
    __syncthreads();                              // input tile fully consumed
    #pragma unroll
    for (int oc = 0; oc < 3; ++oc)
        #pragma unroll
        for (int py = 0; py < 2; ++py)
            #pragma unroll
            for (int px = 0; px < 2; ++px)
                lds[((oc * 8 + 2 * ry0 + py) * 2 + px) * 64 + oxi] = acc[oc][py * 2 + px];
    __syncthreads();

    const int oybase = 2 * oyi0;
    for (int i = tid; i < 3 * 8 * 127; i += 256) {
        const int ox = i % 127;
        const int rr = i / 127;                   // 0..23
        const int ry = rr % 8;
        const int oc = rr / 8;
        const int oy = oybase + ry;
        if (oy < 127) {                           // row 127 doesn't exist (last block only)
            float vv = lds[((oc * 8 + ry) * 2 + (ox & 1)) * 64 + (ox >> 1)];
            out[(((size_t)b * 3 + oc) * 127 + oy) * 127 + ox] = vv;
        }
    }
}

// ---------------------------------------------------------------------------
// per-sample xcorr, 16-way channel split, 2 x-px/thread.
// grid (nb, 16), 192 thr.  out[b*289+p] += partial (atomic; pre-zeroed).
__global__ void xcorr_split_kernel(const float* __restrict__ f, const float* __restrict__ af,
                                   float* __restrict__ out)
{
    const int b = blockIdx.x, g = blockIdx.y;
    const int idx = threadIdx.x;
    if (idx >= 153) return;                    // 17 rows x 9 x-tiles
    const int oy = idx / 9, tx = idx - oy * 9, ox = tx * 2;
    const float* fb = f + ((size_t)b * 64 + g * 4) * 900 + oy * 30 + ox;
    const float* ab = af + g * 4 * 196;
    float a0 = 0.0f, a1 = 0.0f;
    for (int c = 0; c < 4; ++c) {
        const float* fc = fb + c * 900;
        const float* ac = ab + c * 196;
        #pragma unroll
        for (int ky = 0; ky < 14; ++ky) {
            const float* fr = fc + ky * 30;
            const float* ar = ac + ky * 14;    // uniform -> s_load
            float v[15];
            #pragma unroll
            for (int k = 0; k < 15; ++k) v[k] = fr[k];
            #pragma unroll
            for (int k = 0; k < 14; ++k) {
                float wv = ar[k];
                a0 = fmaf(v[k],     wv, a0);
                a1 = fmaf(v[k + 1], wv, a1);
            }
        }
    }
    atomicAdd(&out[b * 289 + oy * 17 + ox], a0);
    if (ox + 1 < 17) atomicAdd(&out[b * 289 + oy * 17 + ox + 1], a1);
}

// ---------------------------------------------------------------------------
extern "C" void kernel_launch(void* const* d_in, const int* in_sizes, int n_in,
                              void* d_out, int out_size, void* d_ws, size_t ws_size,
                              hipStream_t stream)
{
    const float* pos         = (const float*)d_in[0];
    const float* neg         = (const float*)d_in[1];
    const float* pos_crop    = (const float*)d_in[2];
    const float* eps         = (const float*)d_in[3];
    const float* anchor_crop = (const float*)d_in[4];
    const float* ew1 = (const float*)d_in[5];  const float* eb1 = (const float*)d_in[6];
    const float* ew2 = (const float*)d_in[7];  const float* eb2 = (const float*)d_in[8];
    const float* ew3 = (const float*)d_in[9];  const float* eb3 = (const float*)d_in[10];
    const float* mw  = (const float*)d_in[11]; const float* mb  = (const float*)d_in[12];
    const float* lw  = (const float*)d_in[13]; const float* lb  = (const float*)d_in[14];
    const float* dw0 = (const float*)d_in[15]; const float* db0 = (const float*)d_in[16];
    const float* dw1 = (const float*)d_in[17]; const float* db1 = (const float*)d_in[18];
    const float* dw2 = (const float*)d_in[19]; const float* db2 = (const float*)d_in[20];
    const float* dw3 = (const float*)d_in[21]; const float* db3 = (const float*)d_in[22];

    float* out = (float*)d_out;
    float* ws  = (float*)d_ws;

    // output offsets (floats): anchor, cxp, cxn, recon, mu, logvar
    float* o_anchor = out;
    float* o_cxp    = out + 3096768;
    float* o_cxn    = out + 3115264;
    float* o_recon  = out + 3133760;
    float* o_mu     = out + 6230528;
    float* o_lv     = out + 6631936;

    // ---- workspace: AF persistent + arena (adaptive chunk sizes from ws_size)
    float* AF = ws;                 // anchor features 64*14*14
    float* A  = ws + 12544;
    const long budget = (long)(ws_size / 4) - 12544;

    // Phase B (VAE enc): E1 padded (32 x 62 x stride 64 = 126976/spl),
    // E2 padded (64 x 30 x stride 32 = 61440/spl), CH3 dense 802816.
    const int CBV = budget >= 12861440L ? 64 : budget >= 6832128L ? 32
                  : budget >= 3817472L ? 16 : 8;
    float* E1  = A;                                   // CBV*126976
    float* E2  = A + (size_t)CBV * 126976;            // CBV*61440
    float* CH3 = E2 + (size_t)CBV * 61440;            // 64*64*196 (persistent in phase B)
    // Decoder
    const bool dec_full = budget >= 6983680L;
    float* Z   = A;                 // 64*32*14*14
    float* D0  = A + 401408;        // 64*64*14*14
    float* D1  = A + 1204224;       // 64*32*30*30
    float* D2  = A + 3047424;       // 64*16*62*62 (full mode)
    float* D2c = A;                 // 16*16*62*62 (chunk mode; overlays dead Z/D0)
    // Phase C (branches): F1 padded (32 x 126 x stride 128) = CB*516096 ;
    // F2 padded (64 x 62 x stride 64) = CB*253952 ; F3 overlays F1.
    // CB=64 tier (R13: pair4 2048 blocks = occupancy win, +18 us total).
    const int CB = budget >= 49283072L ? 64 : budget >= 24641536L ? 32
                 : budget >= 12320768L ? 16 : budget >= 6160384L ? 8 : 4;
    float* F1 = A;
    float* F2 = A + (size_t)CB * 516096;
    float* F3 = A;
    // anchor enc scratch (AH1 stride 64; AH2 stride 32)
    float* AH1 = A;                 // 126976
    float* AH2 = A + 126976;        // 61440

    // 1) anchor output = broadcast input
    bcast_anchor_kernel<<<dim3(189, 64), 256, 0, stream>>>(anchor_crop, o_anchor);

    // 2) anchor encoder, B=1 (L1 padded out; L2/L3 float4-form)
    conv4s2_relu_k<4,false><<<dim3(4, 8, 1), 256, 0, stream>>>(anchor_crop, ew1, eb1, AH1, 3, 127, 127, 62, 62, 64);
    conv4s2_relu4_k<4><<<dim3(1, 16, 1), 256, 0, stream>>>(AH1, ew2, eb2, AH2, 32, 62, 64, 30, 30, 32);
    conv4s2_relu4_k<4><<<dim3(1, 16, 1), 256, 0, stream>>>(AH2, ew3, eb3, AF, 64, 30, 32, 14, 14, 14);

    // 3) VAE encoder on pos_crop, CBV-sample chunks -> CH3
    //    L1 OCT=8 -> E1 (stride 64); L2 float4 -> E2 (stride 32); L3 float4 -> dense
    for (int c = 0; c < 64 / CBV; ++c) {
        const float* inp = pos_crop + (size_t)c * CBV * 48387;
        conv4s2_relu_k<8,false><<<dim3(4, 4, CBV), 256, 0, stream>>>(inp, ew1, eb1, E1, 3, 127, 127, 62, 62, 64);
        conv4s2_relu4_k<4><<<dim3(1, 16, CBV), 256, 0, stream>>>(E1, ew2, eb2, E2, 32, 62, 64, 30, 30, 32);
        conv4s2_relu4_k<4><<<dim3(1, 16, CBV), 256, 0, stream>>>(E2, ew3, eb3, CH3 + (size_t)c * CBV * 12544, 64, 30, 32, 14, 14, 14);
    }
    //    head + decoder
    vae_head_kernel<<<1568, 256, 0, stream>>>(CH3, mw, mb, lw, lb, eps, o_mu, o_lv, Z);
    conv1x1_relu_kernel<<<3136, 256, 0, stream>>>(Z, dw0, db0, D0, 32, 64, 196, 64*64*196);
    // deconv1: 14->30, H2=W2=15, 225 px -> 1 tile
    deconv4s2_relu_k<4><<<dim3(1, 8, 64), 256, 0, stream>>>(D0, dw1, db1, D1, 64, 14, 14, 30, 30);
    if (dec_full) {
        // deconv2: 30->62, H2=W2=31, 961 px -> 4 tiles
        deconv4s2_relu_k<4><<<dim3(4, 4, 64), 256, 0, stream>>>(D1, dw2, db2, D2, 32, 30, 30, 62, 62);
        deconv5s2_sigmoid_k<<<dim3(16, 64), 256, 0, stream>>>(D2, dw3, db3, o_recon);
    } else {
        for (int c = 0; c < 4; ++c) {
            deconv4s2_relu_k<4><<<dim3(4, 4, 16), 256, 0, stream>>>(D1 + (size_t)c * 16 * 28800, dw2, db2, D2c, 32, 30, 30, 62, 62);
            deconv5s2_sigmoid_k<<<dim3(16, 16), 256, 0, stream>>>(D2c, dw3, db3, o_recon + (size_t)c * 16 * 48387);
        }
    }

    // 4) siamese branches, merged pos+neg stream, CB-sample chunks
    //    L1 OCT=8 -> padded F1 (128); L2 = pair4 -> padded F2 (64);
    //    L3 = float4-form -> dense F3; xcorr unchanged.
    hipMemsetAsync(o_cxp, 0, 2 * 18496 * sizeof(float), stream);  // cxp+cxn contiguous
    const int nchunks = 128 / CB;
    for (int c = 0; c < nchunks; ++c) {
        const int s0 = c * CB;   // CB divides 64 -> no pos/neg straddle
        const float* inp  = (s0 < 64) ? pos + (size_t)s0 * 195075 : neg + (size_t)(s0 - 64) * 195075;
        float*       o_cx = (s0 < 64) ? o_cxp + (size_t)s0 * 289  : o_cxn + (size_t)(s0 - 64) * 289;
        conv4s2_relu_k<8,false><<<dim3(16, 4, CB), 256, 0, stream>>>(inp, ew1, eb1, F1, 3, 255, 255, 126, 126, 128);
        conv4s2_pair4_k<<<dim3(2, 16, CB), 256, 0, stream>>>(F1, ew2, eb2, F2, 32, 126, 62, 62);
        conv4s2_relu4_k<4><<<dim3(1, 16, CB), 256, 0, stream>>>(F2, ew3, eb3, F3, 64, 62, 64, 30, 30, 30);
        xcorr_split_kernel<<<dim3(CB, 16), 192, 0, stream>>>(F3, AF, o_cx);
    }
}